// Round 19
// baseline (643.134 us; speedup 1.0000x reference)
//
#include <hip/hip_runtime.h>
#include <hip/hip_bf16.h>
#include <math.h>

#define BB      32
#define CC      256
#define HDIM    56
#define NPIX    3136
#define NHEADS  8
#define HD      32
#define AG      49
#define NGROUPS 32
#define CPG     8
#define SCALE   0.17677669529663687f

typedef short s16x8 __attribute__((ext_vector_type(8)));
typedef float f32x4 __attribute__((ext_vector_type(4)));
typedef unsigned int u32;

// ---------------- W convert: q/k/v/p fp32 (256x256) -> bf16 [1024][256] ----
__global__ __launch_bounds__(256) void convert_w_kernel(
    const float* __restrict__ q, const float* __restrict__ k,
    const float* __restrict__ v, const float* __restrict__ p,
    __bf16* __restrict__ w) {
  const int i = blockIdx.x * 256 + threadIdx.x;  // 0..65535
  const int z = blockIdx.y;
  const float* src = z == 0 ? q : z == 1 ? k : z == 2 ? v : p;
  w[(size_t)z * 65536 + i] = (__bf16)src[i];
}

// ---------------- transpose+convert: fp32 [b][c][n] -> bf16 [b*n][c] -------
__global__ __launch_bounds__(256) void transpose_kernel(
    const float* __restrict__ X, __bf16* __restrict__ Xt) {
  const int nt = blockIdx.x, ct = blockIdx.y, b = blockIdx.z;
  __shared__ __bf16 T[64][72];
  const int t = threadIdx.x;
  const int c0 = ct * 64, n0 = nt * 64;
  {
    const int c = t >> 2;
    const float* src = X + ((size_t)b * CC + c0 + c) * NPIX + n0;
#pragma unroll
    for (int j = 0; j < 4; ++j) {
      const int col = (t & 3) * 16 + j * 4;
      const float4 v = *(const float4*)&src[col];
      T[c][col + 0] = (__bf16)v.x;
      T[c][col + 1] = (__bf16)v.y;
      T[c][col + 2] = (__bf16)v.z;
      T[c][col + 3] = (__bf16)v.w;
    }
  }
  __syncthreads();
  {
    const int n = t >> 2;
    const int cl0 = (t & 3) * 16;
    __bf16* dst = Xt + ((size_t)b * NPIX + n0 + n) * CC + c0 + cl0;
    union { __bf16 e[16]; uint4 u[2]; } buf;
#pragma unroll
    for (int j = 0; j < 16; ++j) buf.e[j] = T[cl0 + j][n];
    *(uint4*)(dst + 0) = buf.u[0];
    *(uint4*)(dst + 8) = buf.u[1];
  }
}

// ---------------- MFMA GEMM, direct-from-global fragments -------------------
// Round-18 lesson: LDS staging was the gemm's own bottleneck (14.45M bank-
// conflict cycles + 16 barrier drains; 2x off BW floor).  K=256 is small:
// both operands' fragments are 16 contiguous bytes at row*256 + k0 + g4*8 --
// load straight from global (W is L1/L2-hot, Xt tile is L2-absorbed; FETCH
// counter proved re-reads don't reach HBM).  No LDS, no barriers.
template <typename T>
__global__ __launch_bounds__(256) void gemm_kernel(
    const __bf16* __restrict__ W, const __bf16* __restrict__ Xt,
    T* __restrict__ O0, T* __restrict__ O1, T* __restrict__ O2) {
  const int bx = blockIdx.x;   // n-tile (64 px)
  const int by = blockIdx.y;   // m-tile (128 ch)
  const int b = blockIdx.z;
  const int t = threadIdx.x;
  const int o0 = by * 128;
  const int wv = t >> 6, ln = t & 63;
  const int wm = wv >> 1, wn = wv & 1;
  const int l15 = ln & 15, g4 = ln >> 4;

  const __bf16* A0 = W + (size_t)(o0 + wm * 64 + l15) * 256 + g4 * 8;
  const __bf16* B0 = Xt +
      ((size_t)b * NPIX + bx * 64 + wn * 32 + l15) * 256 + g4 * 8;

  const f32x4 zz = {0.f, 0.f, 0.f, 0.f};
  f32x4 acc[4][2];
#pragma unroll
  for (int mi = 0; mi < 4; ++mi)
#pragma unroll
    for (int ni = 0; ni < 2; ++ni) acc[mi][ni] = zz;

#pragma unroll
  for (int k0 = 0; k0 < 256; k0 += 32) {
    s16x8 fa[4], fb[2];
#pragma unroll
    for (int mi = 0; mi < 4; ++mi)
      fa[mi] = *(const s16x8*)(A0 + (size_t)mi * 16 * 256 + k0);
#pragma unroll
    for (int ni = 0; ni < 2; ++ni)
      fb[ni] = *(const s16x8*)(B0 + (size_t)ni * 16 * 256 + k0);
#pragma unroll
    for (int mi = 0; mi < 4; ++mi)
#pragma unroll
      for (int ni = 0; ni < 2; ++ni)
        acc[mi][ni] = __builtin_amdgcn_mfma_f32_16x16x32_bf16(
            fa[mi], fb[ni], acc[mi][ni], 0, 0, 0);
  }
#pragma unroll
  for (int mi = 0; mi < 4; ++mi) {
    const int ob = o0 + wm * 64 + mi * 16 + g4 * 4;
#pragma unroll
    for (int ni = 0; ni < 2; ++ni) {
      const int n = bx * 64 + wn * 32 + ni * 16 + l15;
#pragma unroll
      for (int r = 0; r < 4; ++r) {
        const int oo = ob + r;
        T* dst = (oo < 256) ? O0 : (oo < 512) ? O1 : O2;
        dst[((size_t)b * CC + (oo & 255)) * NPIX + n] = (T)acc[mi][ni][r];
      }
    }
  }
}

// ---------------- GN stats from raw bf16 qkv: direct scale/shift ------------
__global__ __launch_bounds__(256) void qkvstat_kernel(
    const __bf16* __restrict__ qkv, const float* __restrict__ qgw,
    const float* __restrict__ qgb, const float* __restrict__ kgw,
    const float* __restrict__ kgb, const float* __restrict__ vgw,
    const float* __restrict__ vgb, float* __restrict__ sc,
    float* __restrict__ sh) {
  const int zg = blockIdx.x, b = blockIdx.y;
  const int t = threadIdx.x, w = t >> 6, ln = t & 63;
  __shared__ float Ss[8], Qs[8];
  __shared__ float st[2];
#pragma unroll
  for (int j = 0; j < 2; ++j) {
    const int ch = zg * 8 + w * 2 + j;
    const int z = ch >> 8, c = ch & 255;
    const __bf16* row =
        qkv + ((size_t)z * BB * CC + (size_t)b * CC + c) * NPIX;
    float S = 0.f, Q = 0.f;
    for (int i = ln; i < 392; i += 64) {
      union { uint4 u; __bf16 e[8]; } v;
      v.u = *(const uint4*)&row[i * 8];
#pragma unroll
      for (int e = 0; e < 8; ++e) {
        const float f = (float)v.e[e];
        S += f;
        Q += f * f;
      }
    }
#pragma unroll
    for (int off = 32; off > 0; off >>= 1) {
      S += __shfl_down(S, off);
      Q += __shfl_down(Q, off);
    }
    if (ln == 0) {
      Ss[w * 2 + j] = S;
      Qs[w * 2 + j] = Q;
    }
  }
  __syncthreads();
  if (t == 0) {
    float S = 0.f, Q = 0.f;
#pragma unroll
    for (int i = 0; i < 8; ++i) {
      S += Ss[i];
      Q += Qs[i];
    }
    const float m = S / 25088.f;
    const float var = Q / 25088.f - m * m;
    st[0] = m;
    st[1] = rsqrtf(var + 1e-5f);
  }
  __syncthreads();
  if (t < 8) {
    const int ch = zg * 8 + t;
    const int z = ch >> 8, c = ch & 255;
    const float gw = z == 0 ? qgw[c] : z == 1 ? kgw[c] : vgw[c];
    const float gb = z == 0 ? qgb[c] : z == 1 ? kgb[c] : vgb[c];
    const float s = gw * st[1];
    sc[(size_t)b * 768 + ch] = s;
    sh[(size_t)b * 768 + ch] = gb - st[0] * s;
  }
}

// ---------------- GroupNorm (final p-conv only) -----------------------------
__global__ __launch_bounds__(256) void gn_kernel(
    const float* __restrict__ in, const float* __restrict__ gw,
    const float* __restrict__ gb, float* __restrict__ out) {
  const int g = blockIdx.x, b = blockIdx.y;
  const float* p = in + ((size_t)b * CC + g * CPG) * NPIX;
  float* q = out + ((size_t)b * CC + g * CPG) * NPIX;
  const int tid = threadIdx.x;
  const int M4 = CPG * NPIX / 4;
  const float4* p4 = (const float4*)p;
  float4* q4 = (float4*)q;
  float4 r[25];
  float s = 0.f, ss = 0.f;
#pragma unroll
  for (int j = 0; j < 25; ++j) {
    const int i = tid + j * 256;
    if (i < M4) {
      const float4 v = p4[i];
      r[j] = v;
      s += v.x + v.y + v.z + v.w;
      ss += v.x * v.x + v.y * v.y + v.z * v.z + v.w * v.w;
    }
  }
#pragma unroll
  for (int off = 32; off > 0; off >>= 1) {
    s += __shfl_down(s, off);
    ss += __shfl_down(ss, off);
  }
  __shared__ float wsum[4], wsq[4], stat[2];
  const int wv = tid >> 6, lnn = tid & 63;
  if (lnn == 0) { wsum[wv] = s; wsq[wv] = ss; }
  __syncthreads();
  if (tid == 0) {
    float S = wsum[0] + wsum[1] + wsum[2] + wsum[3];
    float SS = wsq[0] + wsq[1] + wsq[2] + wsq[3];
    const float inv_m = 1.f / (CPG * NPIX);
    float mean = S * inv_m;
    float var = SS * inv_m - mean * mean;
    stat[0] = mean;
    stat[1] = rsqrtf(var + 1e-5f);
  }
  __syncthreads();
  const float mean = stat[0], inv = stat[1];
#pragma unroll
  for (int j = 0; j < 25; ++j) {
    const int i = tid + j * 256;
    if (i < M4) {
      const int ch = g * CPG + i / (NPIX / 4);
      const float w = gw[ch] * inv, bia = gb[ch];
      float4 v = r[j];
      v.x = (v.x - mean) * w + bia;
      v.y = (v.y - mean) * w + bia;
      v.z = (v.z - mean) * w + bia;
      v.w = (v.w - mean) * w + bia;
      q4[i] = v;
    }
  }
}

// ---------------- agent-token pool (raw bf16 q; affine after averaging) -----
__global__ __launch_bounds__(64) void pool_kernel(
    const __bf16* __restrict__ q, const float* __restrict__ sc,
    const float* __restrict__ sh, float* __restrict__ at) {
  const int bc = blockIdx.x;
  const int a = threadIdx.x;
  if (a >= AG) return;
  const int b = bc >> 8, c = bc & 255;
  const int py = a / 7, px = a % 7;
  const __bf16* p = q + (size_t)bc * NPIX + (py * 8) * HDIM + px * 8;
  float s = 0.f;
#pragma unroll
  for (int y = 0; y < 8; ++y)
#pragma unroll
    for (int x = 0; x < 8; ++x) s += (float)p[y * HDIM + x];
  at[(size_t)bc * AG + a] =
      s * (1.f / 64.f) * sc[(size_t)b * 768 + c] + sh[(size_t)b * 768 + c];
}

// ---------------- bias precompute -------------------------------------------
__device__ __forceinline__ float bilin7(const float* __restrict__ src, int y,
                                        int x) {
  float sy = fminf(fmaxf((y + 0.5f) * 0.125f - 0.5f, 0.f), 6.f);
  float sx = fminf(fmaxf((x + 0.5f) * 0.125f - 0.5f, 0.f), 6.f);
  int y0 = (int)sy, x0 = (int)sx;
  int y1 = min(y0 + 1, 6), x1 = min(x0 + 1, 6);
  float fy = sy - y0, fx = sx - x0;
  return (1.f - fy) * ((1.f - fx) * src[y0 * 7 + x0] + fx * src[y0 * 7 + x1]) +
         fy * ((1.f - fx) * src[y1 * 7 + x0] + fx * src[y1 * 7 + x1]);
}

// pbt[h][n][64-padded] (pad zeroed via memset)
__global__ __launch_bounds__(256) void bias1_kernel(
    const float* __restrict__ an, const float* __restrict__ ah,
    const float* __restrict__ aw, float* __restrict__ pbt) {
  const int ha = blockIdx.x;
  const int h = ha / AG, a = ha % AG;
  const float* src = an + (size_t)ha * 49;
  const float* ahp = ah + (size_t)ha * HDIM;
  const float* awp = aw + (size_t)ha * HDIM;
  for (int n = threadIdx.x; n < NPIX; n += 256) {
    const int y = n / HDIM, x = n % HDIM;
    pbt[((size_t)h * NPIX + n) * 64 + a] = bilin7(src, y, x) + ahp[y] + awp[x];
  }
}

// fill ab2 with -1e9 (pad agents -> exp()==0)
__global__ __launch_bounds__(256) void fill_kernel(float* __restrict__ p,
                                                   int n4) {
  const int i = blockIdx.x * 256 + threadIdx.x;
  if (i < n4) {
    float4 v = make_float4(-1e9f, -1e9f, -1e9f, -1e9f);
    *(float4*)&p[i * 4] = v;
  }
}

// ab2[h][n][64-padded]
__global__ __launch_bounds__(256) void bias2_kernel(
    const float* __restrict__ na, const float* __restrict__ hab,
    const float* __restrict__ wab, float* __restrict__ ab2) {
  const int ha = blockIdx.x;
  const int h = ha / AG, a = ha % AG;
  const float* src = na + (size_t)ha * 49;
  for (int n = threadIdx.x; n < NPIX; n += 256) {
    const int y = n / HDIM, x = n % HDIM;
    ab2[((size_t)h * NPIX + n) * 64 + a] =
        bilin7(src, y, x) + hab[((size_t)h * HDIM + y) * AG + a] +
        wab[((size_t)h * HDIM + x) * AG + a];
  }
}

// ---------------- pure transpose: bf16 [b][c][n] (head) -> bf16 [bh][n][32] -
__global__ __launch_bounds__(256) void tr_k_kernel(
    const __bf16* __restrict__ K, __bf16* __restrict__ Kt) {
  const int nt = blockIdx.x, h = blockIdx.y, b = blockIdx.z;
  const int n0 = nt * 64;
  __shared__ __bf16 T[32][72];
  const int t = threadIdx.x;
  {
    const int d = t >> 3, c8 = (t & 7) * 8;
    *(uint4*)&T[d][c8] =
        *(const uint4*)&K[((size_t)(b * CC + h * HD + d)) * NPIX + n0 + c8];
  }
  __syncthreads();
  {
    const int n = t >> 2, d0 = (t & 3) * 8;
    union { __bf16 e[8]; uint4 u; } buf;
#pragma unroll
    for (int j = 0; j < 8; ++j) buf.e[j] = T[d0 + j][n];
    *(uint4*)&Kt[((size_t)(b * NHEADS + h) * NPIX + n0 + n) * HD + d0] = buf.u;
  }
}

// ---------------- stage 1 (MFMA): GN affines folded -------------------------
__global__ __launch_bounds__(256) void stage1_kernel(
    const __bf16* __restrict__ Kt, const __bf16* __restrict__ V,
    const float* __restrict__ at, const float* __restrict__ pbt,
    const float* __restrict__ sc, const float* __restrict__ sh,
    float* __restrict__ av) {
  const int bh = blockIdx.x;
  const int b = bh >> 3, h = bh & 7;
  const int t = threadIdx.x;
  const int w = t >> 6, ln = t & 63;
  const int l15 = ln & 15, g4 = ln >> 4;

  __shared__ float atraw[64][33];
  __shared__ float sck_s[32], shk_s[32];
  __shared__ float cb_s[64];
  __shared__ __bf16 at_s[64][40];
  __shared__ __bf16 Es[4][64][40];
  __shared__ float avs[4][64][33];
  __shared__ float Ls[4][64];

  if (t < 32) {
    const size_t si = (size_t)b * 768 + 256 + h * HD + t;
    sck_s[t] = sc[si];
    shk_s[t] = sh[si];
  }
  for (int i = t; i < 64 * 32; i += 256) {
    const int d = i >> 6, a = i & 63;
    atraw[a][d] =
        (a < AG) ? at[((size_t)b * CC + h * HD + d) * AG + a] * SCALE : 0.f;
  }
  __syncthreads();
  if (t < 64) {
    float s = 0.f;
#pragma unroll
    for (int d = 0; d < HD; ++d) {
      const float v = atraw[t][d];
      s += v * shk_s[d];
      at_s[t][d] = (__bf16)(v * sck_s[d]);
    }
    cb_s[t] = s;
  }
  __syncthreads();

  s16x8 fa[4];
  float4 cbv[4];
#pragma unroll
  for (int mt = 0; mt < 4; ++mt) {
    fa[mt] = *(const s16x8*)&at_s[mt * 16 + l15][g4 * 8];
    cbv[mt] = *(const float4*)&cb_s[mt * 16 + g4 * 4];
  }

  const __bf16* Ktb = Kt + (size_t)bh * NPIX * HD;
  const __bf16* Vcb = V + ((size_t)b * CC + h * HD) * NPIX;
  const float* pbh = pbt + (size_t)h * NPIX * 64;

  const f32x4 zz = {0.f, 0.f, 0.f, 0.f};
  f32x4 avacc[4][2];
#pragma unroll
  for (int mt = 0; mt < 4; ++mt) {
    avacc[mt][0] = zz;
    avacc[mt][1] = zz;
  }
  float lsum[4][4] = {};

  for (int ct = w; ct < 98; ct += 4) {
    const int nc0 = ct * 32;
    f32x4 c0[4], c1[4];
    {
      const s16x8 kf0 =
          *(const s16x8*)&Ktb[(size_t)(nc0 + l15) * HD + g4 * 8];
      const s16x8 kf1 =
          *(const s16x8*)&Ktb[(size_t)(nc0 + 16 + l15) * HD + g4 * 8];
#pragma unroll
      for (int mt = 0; mt < 4; ++mt) {
        c0[mt] = __builtin_amdgcn_mfma_f32_16x16x32_bf16(fa[mt], kf0, zz, 0, 0, 0);
        c1[mt] = __builtin_amdgcn_mfma_f32_16x16x32_bf16(fa[mt], kf1, zz, 0, 0, 0);
      }
    }
#pragma unroll
    for (int mt = 0; mt < 4; ++mt) {
      const int a0 = mt * 16 + g4 * 4;
      {
        const float4 bi =
            *(const float4*)&pbh[(size_t)(nc0 + l15) * 64 + a0];
        const float e0 = __expf(c0[mt][0] + bi.x + cbv[mt].x);
        const float e1 = __expf(c0[mt][1] + bi.y + cbv[mt].y);
        const float e2 = __expf(c0[mt][2] + bi.z + cbv[mt].z);
        const float e3 = __expf(c0[mt][3] + bi.w + cbv[mt].w);
        lsum[mt][0] += e0; lsum[mt][1] += e1;
        lsum[mt][2] += e2; lsum[mt][3] += e3;
        Es[w][a0 + 0][l15] = (__bf16)e0;
        Es[w][a0 + 1][l15] = (__bf16)e1;
        Es[w][a0 + 2][l15] = (__bf16)e2;
        Es[w][a0 + 3][l15] = (__bf16)e3;
      }
      {
        const float4 bi =
            *(const float4*)&pbh[(size_t)(nc0 + 16 + l15) * 64 + a0];
        const float e0 = __expf(c1[mt][0] + bi.x + cbv[mt].x);
        const float e1 = __expf(c1[mt][1] + bi.y + cbv[mt].y);
        const float e2 = __expf(c1[mt][2] + bi.z + cbv[mt].z);
        const float e3 = __expf(c1[mt][3] + bi.w + cbv[mt].w);
        lsum[mt][0] += e0; lsum[mt][1] += e1;
        lsum[mt][2] += e2; lsum[mt][3] += e3;
        Es[w][a0 + 0][16 + l15] = (__bf16)e0;
        Es[w][a0 + 1][16 + l15] = (__bf16)e1;
        Es[w][a0 + 2][16 + l15] = (__bf16)e2;
        Es[w][a0 + 3][16 + l15] = (__bf16)e3;
      }
    }
    asm volatile("s_waitcnt lgkmcnt(0)" ::: "memory");
    const s16x8 vf0 =
        *(const s16x8*)&Vcb[(size_t)(l15) * NPIX + nc0 + g4 * 8];
    const s16x8 vf1 =
        *(const s16x8*)&Vcb[(size_t)(16 + l15) * NPIX + nc0 + g4 * 8];
#pragma unroll
    for (int mt = 0; mt < 4; ++mt) {
      const s16x8 ef = *(const s16x8*)&Es[w][mt * 16 + l15][g4 * 8];
      avacc[mt][0] =
          __builtin_amdgcn_mfma_f32_16x16x32_bf16(ef, vf0, avacc[mt][0], 0, 0, 0);
      avacc[mt][1] =
          __builtin_amdgcn_mfma_f32_16x16x32_bf16(ef, vf1, avacc[mt][1], 0, 0, 0);
    }
  }

#pragma unroll
  for (int mt = 0; mt < 4; ++mt)
#pragma unroll
    for (int r = 0; r < 4; ++r) {
      float v = lsum[mt][r];
      v += __shfl_xor(v, 1);
      v += __shfl_xor(v, 2);
      v += __shfl_xor(v, 4);
      v += __shfl_xor(v, 8);
      if (l15 == 0) Ls[w][mt * 16 + g4 * 4 + r] = v;
    }
#pragma unroll
  for (int mt = 0; mt < 4; ++mt)
#pragma unroll
    for (int dt = 0; dt < 2; ++dt)
#pragma unroll
      for (int r = 0; r < 4; ++r)
        avs[w][mt * 16 + g4 * 4 + r][dt * 16 + l15] = avacc[mt][dt][r];
  __syncthreads();
  for (int i = t; i < AG * HD; i += 256) {
    const int a = i >> 5, d = i & 31;
    const float L = Ls[0][a] + Ls[1][a] + Ls[2][a] + Ls[3][a];
    const float s = avs[0][a][d] + avs[1][a][d] + avs[2][a][d] + avs[3][a][d];
    const size_t si = (size_t)b * 768 + 512 + h * HD + d;
    av[((size_t)bh * AG + a) * HD + d] = (s / L) * sc[si] + sh[si];
  }
}

// ---------------- stage 2 (MFMA): Q affine folded into B-fragment -----------
__global__ __launch_bounds__(256) void stage2_kernel(
    const __bf16* __restrict__ Qt, const float* __restrict__ at,
    const float* __restrict__ av, const float* __restrict__ ab2,
    const float* __restrict__ sc, const float* __restrict__ sh,
    float* __restrict__ XO) {
  const int s = blockIdx.x;
  const int bh = blockIdx.y;
  const int b = bh >> 3, h = bh & 7;
  const int t = threadIdx.x;
  const int w = t >> 6, ln = t & 63;
  const int l15 = ln & 15, g4 = ln >> 4;

  __shared__ float atraw[64][33];
  __shared__ float scq_s[32], shq_s[32];
  __shared__ float cb2_s[64];
  __shared__ __bf16 atb[64][40];
  __shared__ __bf16 avbT[32][72];
  __shared__ __bf16 Es[4][16][72];
  __shared__ float Os[4][16][33];

  if (t < 32) {
    const size_t si = (size_t)b * 768 + h * HD + t;
    scq_s[t] = sc[si];
    shq_s[t] = sh[si];
  }
  for (int i = t; i < 64 * 32; i += 256) {
    const int d = i >> 6, a = i & 63;
    atraw[a][d] =
        (a < AG) ? at[((size_t)b * CC + h * HD + d) * AG + a] * SCALE : 0.f;
  }
  for (int i = t; i < 32 * 64; i += 256) {
    const int d = i >> 6, a = i & 63;
    const float v = (a < AG) ? av[((size_t)bh * AG + a) * HD + d] : 0.f;
    avbT[d][a] = (__bf16)v;
  }
  __syncthreads();
  if (t < 64) {
    float s2 = 0.f;
#pragma unroll
    for (int d = 0; d < HD; ++d) {
      const float v = atraw[t][d];
      s2 += v * shq_s[d];
      atb[t][d] = (__bf16)(v * scq_s[d]);
    }
    cb2_s[t] = s2;
  }
  __syncthreads();

  s16x8 at_fB[4];
  float q2b[4];
#pragma unroll
  for (int atile = 0; atile < 4; ++atile) {
    at_fB[atile] = *(const s16x8*)&atb[atile * 16 + l15][g4 * 8];
    q2b[atile] = cb2_s[atile * 16 + l15];
  }
  s16x8 av_fB[2][2];
#pragma unroll
  for (int dt = 0; dt < 2; ++dt)
#pragma unroll
    for (int ks = 0; ks < 2; ++ks)
      av_fB[dt][ks] = *(const s16x8*)&avbT[dt * 16 + l15][ks * 32 + g4 * 8];

  const __bf16* Qtb = Qt + (size_t)bh * NPIX * HD;
  const float* abh = ab2 + (size_t)h * NPIX * 64;
  float* Ob = XO + ((size_t)b * CC + h * HD) * NPIX;
  const f32x4 zz = {0.f, 0.f, 0.f, 0.f};
  const int nbase = s * 784;

  for (int ct = w; ct < 49; ct += 4) {
    const int n0 = nbase + ct * 16;
    const s16x8 qf = *(const s16x8*)&Qtb[(size_t)(n0 + l15) * HD + g4 * 8];
    f32x4 c[4];
#pragma unroll
    for (int atile = 0; atile < 4; ++atile)
      c[atile] = __builtin_amdgcn_mfma_f32_16x16x32_bf16(qf, at_fB[atile], zz, 0, 0, 0);
    float Lr[4];
#pragma unroll
    for (int r = 0; r < 4; ++r) {
      const int n = n0 + g4 * 4 + r;
      const float* brow = &abh[(size_t)n * 64];
      float es[4];
#pragma unroll
      for (int atile = 0; atile < 4; ++atile) {
        const float e = __expf(c[atile][r] + brow[atile * 16 + l15] + q2b[atile]);
        es[atile] = e;
        Es[w][g4 * 4 + r][atile * 16 + l15] = (__bf16)e;
      }
      float sr = (es[0] + es[1]) + (es[2] + es[3]);
      sr += __shfl_xor(sr, 1);
      sr += __shfl_xor(sr, 2);
      sr += __shfl_xor(sr, 4);
      sr += __shfl_xor(sr, 8);
      Lr[r] = sr;
    }
    asm volatile("s_waitcnt lgkmcnt(0)" ::: "memory");
    const s16x8 ef0 = *(const s16x8*)&Es[w][l15][g4 * 8];
    const s16x8 ef1 = *(const s16x8*)&Es[w][l15][32 + g4 * 8];
    f32x4 o0 = __builtin_amdgcn_mfma_f32_16x16x32_bf16(ef0, av_fB[0][0], zz, 0, 0, 0);
    o0 = __builtin_amdgcn_mfma_f32_16x16x32_bf16(ef1, av_fB[0][1], o0, 0, 0, 0);
    f32x4 o1 = __builtin_amdgcn_mfma_f32_16x16x32_bf16(ef0, av_fB[1][0], zz, 0, 0, 0);
    o1 = __builtin_amdgcn_mfma_f32_16x16x32_bf16(ef1, av_fB[1][1], o1, 0, 0, 0);
#pragma unroll
    for (int r = 0; r < 4; ++r) {
      const float inv = 1.f / Lr[r];
      Os[w][g4 * 4 + r][l15] = o0[r] * inv;
      Os[w][g4 * 4 + r][16 + l15] = o1[r] * inv;
    }
    asm volatile("s_waitcnt lgkmcnt(0)" ::: "memory");
#pragma unroll
    for (int it = 0; it < 8; ++it) {
      const int d = it * 4 + g4;
      Ob[(size_t)d * NPIX + n0 + l15] = Os[w][l15][d];
    }
  }
}

// ---------------- depthwise 3x3 conv, LDS-tiled, affine on bf16 load --------
__global__ __launch_bounds__(256) void dwconv_kernel(
    const __bf16* __restrict__ V, const float* __restrict__ sc,
    const float* __restrict__ sh, const float* __restrict__ w,
    const float* __restrict__ bias, float* __restrict__ XO) {
  const int bc = blockIdx.x;
  const int c = bc % CC;
  const int b = bc >> 8;
  const int tid = threadIdx.x;
  __shared__ float T[58][60];
  float* Tf = &T[0][0];
  for (int i = tid; i < 58 * 60; i += 256) Tf[i] = 0.f;
  __syncthreads();
  const size_t si = (size_t)b * 768 + 512 + c;
  const float scl = sc[si], shf = sh[si];
  const __bf16* src = V + (size_t)bc * NPIX;
  for (int i = tid; i < 392; i += 256) {
    const int y = i / 7, x8 = (i % 7) * 8;
    union { uint4 u; __bf16 e[8]; } raw;
    raw.u = *(const uint4*)&src[y * HDIM + x8];
#pragma unroll
    for (int j = 0; j < 8; ++j)
      T[y + 1][x8 + 1 + j] = (float)raw.e[j] * scl + shf;
  }
  __syncthreads();
  float k[9];
#pragma unroll
  for (int i = 0; i < 9; ++i) k[i] = w[c * 9 + i];
  const float bb = bias[c];
  float* dst = XO + (size_t)bc * NPIX;
  for (int n = tid; n < NPIX; n += 256) {
    const int y = n / HDIM, x = n % HDIM;
    const float s = bb +
        k[0] * T[y][x]     + k[1] * T[y][x + 1]     + k[2] * T[y][x + 2] +
        k[3] * T[y + 1][x] + k[4] * T[y + 1][x + 1] + k[5] * T[y + 1][x + 2] +
        k[6] * T[y + 2][x] + k[7] * T[y + 2][x + 1] + k[8] * T[y + 2][x + 2];
    dst[n] += s;
  }
}

// ---------------- host launch ------------------------------------------------
extern "C" void kernel_launch(void* const* d_in, const int* in_sizes, int n_in,
                              void* d_out, int out_size, void* d_ws,
                              size_t ws_size, hipStream_t stream) {
  const float* x     = (const float*)d_in[0];
  const float* q_w   = (const float*)d_in[1];
  const float* q_gw  = (const float*)d_in[2];
  const float* q_gb  = (const float*)d_in[3];
  const float* k_w   = (const float*)d_in[4];
  const float* k_gw  = (const float*)d_in[5];
  const float* k_gb  = (const float*)d_in[6];
  const float* v_w   = (const float*)d_in[7];
  const float* v_gw  = (const float*)d_in[8];
  const float* v_gb  = (const float*)d_in[9];
  const float* p_w   = (const float*)d_in[10];
  const float* p_gw  = (const float*)d_in[11];
  const float* p_gb  = (const float*)d_in[12];
  const float* dwc_w = (const float*)d_in[13];
  const float* dwc_b = (const float*)d_in[14];
  const float* an_b  = (const float*)d_in[15];
  const float* na_b  = (const float*)d_in[16];
  const float* ah_b  = (const float*)d_in[17];
  const float* aw_b  = (const float*)d_in[18];
  const float* ha_b  = (const float*)d_in[19];
  const float* wa_b  = (const float*)d_in[20];
  float* out = (float*)d_out;

  const size_t SZ_FEAT = (size_t)BB * CC * NPIX;       // 25,690,112 elements
  const size_t SZ_AT   = (size_t)BB * CC * AG;
  const size_t SZ_PBT  = (size_t)NHEADS * NPIX * 64;   // padded bias (x2)
  const size_t SZ_AV   = (size_t)BB * NHEADS * AG * HD;
  const size_t SZ_SC   = (size_t)BB * 768;             // GN scale/shift (x2)
  const size_t need =
      3 * SZ_FEAT * sizeof(__bf16) +
      (SZ_FEAT + SZ_AT + 2 * SZ_PBT + SZ_AV + 2 * SZ_SC) * sizeof(float) +
      1024 * 256 * sizeof(__bf16);
  if (ws_size < need) return;  // insufficient scratch: fail visibly

  __bf16* qbf = (__bf16*)d_ws;       // raw bf16 q from gemm (k,v contiguous)
  __bf16* kbf = qbf + SZ_FEAT;
  __bf16* vbf = kbf + SZ_FEAT;
  float* xo  = (float*)(vbf + SZ_FEAT);  // stage2 out + dwconv accum (fp32)
  float* at  = xo + SZ_FEAT;
  float* pbt = at + SZ_AT;
  float* ab2 = pbt + SZ_PBT;
  float* av  = ab2 + SZ_PBT;
  __bf16* wbf = (__bf16*)(av + SZ_AV);   // [1024][256]
  float* sc = (float*)(wbf + 1024 * 256);
  float* sh = sc + SZ_SC;

  // d_out scratch timeline: xbf front (QKV gemm input, dead after);
  // Kt back half -> Qt reuses after stage1; dead before final GN.
  __bf16* xbf = (__bf16*)d_out;
  __bf16* Kt  = (__bf16*)((char*)d_out + SZ_FEAT * 2);
  __bf16* Qt  = Kt;

  const dim3 ggrid(NGROUPS, BB);
  const dim3 tgrid(49, 4, BB);

  convert_w_kernel<<<dim3(256, 4), 256, 0, stream>>>(q_w, k_w, v_w, p_w, wbf);
  transpose_kernel<<<tgrid, 256, 0, stream>>>(x, xbf);
  gemm_kernel<__bf16><<<dim3(49, 6, BB), 256, 0, stream>>>(wbf, xbf, qbf, kbf,
                                                           vbf);
  qkvstat_kernel<<<dim3(96, BB), 256, 0, stream>>>(qbf, q_gw, q_gb, k_gw,
                                                   k_gb, v_gw, v_gb, sc, sh);

  pool_kernel<<<BB * CC, 64, 0, stream>>>(qbf, sc, sh, at);
  hipMemsetAsync(pbt, 0, SZ_PBT * sizeof(float), stream);
  bias1_kernel<<<NHEADS * AG, 256, 0, stream>>>(an_b, ah_b, aw_b, pbt);
  fill_kernel<<<(int)(SZ_PBT / 4 + 255) / 256, 256, 0, stream>>>(
      ab2, (int)(SZ_PBT / 4));
  bias2_kernel<<<NHEADS * AG, 256, 0, stream>>>(na_b, ha_b, wa_b, ab2);

  tr_k_kernel<<<dim3(49, NHEADS, BB), 256, 0, stream>>>(kbf, Kt);
  stage1_kernel<<<BB * NHEADS, 256, 0, stream>>>(Kt, vbf, at, pbt, sc, sh, av);

  tr_k_kernel<<<dim3(49, NHEADS, BB), 256, 0, stream>>>(qbf, Qt);
  stage2_kernel<<<dim3(4, BB * NHEADS), 256, 0, stream>>>(Qt, at, av, ab2, sc,
                                                          sh, xo);
  dwconv_kernel<<<BB * CC, 256, 0, stream>>>(vbf, sc, sh, dwc_w, dwc_b, xo);

  transpose_kernel<<<tgrid, 256, 0, stream>>>(xo, xbf);
  gemm_kernel<float><<<dim3(49, 2, BB), 256, 0, stream>>>(wbf + 768 * 256,
                                                          xbf, xo, xo, xo);
  gn_kernel<<<ggrid, 256, 0, stream>>>(xo, p_gw, p_gb, out);
}

// Round 20
// 499.427 us; speedup vs baseline: 1.2877x; 1.2877x over previous
//
#include <hip/hip_runtime.h>
#include <hip/hip_bf16.h>
#include <math.h>

#define BB      32
#define CC      256
#define HDIM    56
#define NPIX    3136
#define NHEADS  8
#define HD      32
#define AG      49
#define NGROUPS 32
#define CPG     8
#define SCALE   0.17677669529663687f

typedef short s16x8 __attribute__((ext_vector_type(8)));
typedef float f32x4 __attribute__((ext_vector_type(4)));
typedef unsigned int u32;

#define GLL16(g, l)                                                        \
  __builtin_amdgcn_global_load_lds(                                        \
      (const u32 __attribute__((address_space(1)))*)(g),                   \
      (u32 __attribute__((address_space(3)))*)(l), 16, 0, 0)

// ---------------- W convert: q/k/v/p fp32 (256x256) -> bf16 [1024][256] ----
__global__ __launch_bounds__(256) void convert_w_kernel(
    const float* __restrict__ q, const float* __restrict__ k,
    const float* __restrict__ v, const float* __restrict__ p,
    __bf16* __restrict__ w) {
  const int i = blockIdx.x * 256 + threadIdx.x;  // 0..65535
  const int z = blockIdx.y;
  const float* src = z == 0 ? q : z == 1 ? k : z == 2 ? v : p;
  w[(size_t)z * 65536 + i] = (__bf16)src[i];
}

// ---------------- transpose+convert: fp32 [b][c][n] -> bf16 [b*n][c] -------
__global__ __launch_bounds__(256) void transpose_kernel(
    const float* __restrict__ X, __bf16* __restrict__ Xt) {
  const int nt = blockIdx.x, ct = blockIdx.y, b = blockIdx.z;
  __shared__ __bf16 T[64][72];
  const int t = threadIdx.x;
  const int c0 = ct * 64, n0 = nt * 64;
  {
    const int c = t >> 2;
    const float* src = X + ((size_t)b * CC + c0 + c) * NPIX + n0;
#pragma unroll
    for (int j = 0; j < 4; ++j) {
      const int col = (t & 3) * 16 + j * 4;
      const float4 v = *(const float4*)&src[col];
      T[c][col + 0] = (__bf16)v.x;
      T[c][col + 1] = (__bf16)v.y;
      T[c][col + 2] = (__bf16)v.z;
      T[c][col + 3] = (__bf16)v.w;
    }
  }
  __syncthreads();
  {
    const int n = t >> 2;
    const int cl0 = (t & 3) * 16;
    __bf16* dst = Xt + ((size_t)b * NPIX + n0 + n) * CC + c0 + cl0;
    union { __bf16 e[16]; uint4 u[2]; } buf;
#pragma unroll
    for (int j = 0; j < 16; ++j) buf.e[j] = T[cl0 + j][n];
    *(uint4*)(dst + 0) = buf.u[0];
    *(uint4*)(dst + 8) = buf.u[1];
  }
}

// ---------------- MFMA GEMM: LDS-staged, double-buffered --------------------
// Round-19 lesson: direct-from-global fragments (stride-512B/lane, 16 cache
// lines per wave load) are latency-bound: 221us vs LDS-staged 96us.  REVERT
// to r18 LDS staging; cut its overhead with the stage1-verified 2-phase
// pipeline: prefetch k+1 into buf^1 BEFORE computing k, one vmcnt+barrier
// per k-step (8 total vs 16).
template <typename T>
__global__ __launch_bounds__(256) void gemm_kernel(
    const __bf16* __restrict__ W, const __bf16* __restrict__ Xt,
    T* __restrict__ O0, T* __restrict__ O1, T* __restrict__ O2) {
  __shared__ __bf16 As[2][128 * 32];
  __shared__ __bf16 Bs[2][64 * 32];
  const int bx = blockIdx.x;
  const int by = blockIdx.y;
  const int b = blockIdx.z;
  const int t = threadIdx.x;
  const int o0 = by * 128;

  const int ar0 = t >> 2, G = t & 3;
  const int sa0 = G ^ ((ar0 >> 1) & 3);
  const int ar1 = 64 + ar0;
  const int sa1 = G ^ ((ar1 >> 1) & 3);
  const char* wbase = (const char*)W;
  const char* xbase = (const char*)(Xt + ((size_t)b * NPIX + bx * 64) * CC);
  const size_t ga0 = (size_t)(o0 + ar0) * 512 + sa0 * 16;
  const size_t ga1 = (size_t)(o0 + ar1) * 512 + sa1 * 16;
  const size_t gb0 = (size_t)ar0 * 512 + sa0 * 16;

  const int wv = t >> 6, ln = t & 63;
  const int wm = wv >> 1, wn = wv & 1;
  const int l15 = ln & 15, g4 = ln >> 4;

#define G_STAGE(buf, k0)                                                   \
  {                                                                        \
    GLL16(wbase + ga0 + (k0) * 2, (char*)As[buf] + t * 16);                \
    GLL16(wbase + ga1 + (k0) * 2, (char*)As[buf] + 4096 + t * 16);         \
    GLL16(xbase + gb0 + (k0) * 2, (char*)Bs[buf] + t * 16);                \
  }

  const f32x4 zz = {0.f, 0.f, 0.f, 0.f};
  f32x4 acc[4][2];
#pragma unroll
  for (int mi = 0; mi < 4; ++mi)
#pragma unroll
    for (int ni = 0; ni < 2; ++ni) acc[mi][ni] = zz;

  G_STAGE(0, 0);
  asm volatile("s_waitcnt vmcnt(0)");
  __syncthreads();

  int cur = 0;
#pragma unroll
  for (int k0 = 0; k0 < 256; k0 += 32) {
    if (k0 < 224) G_STAGE(cur ^ 1, k0 + 32);
    s16x8 fa[4], fb[2];
#pragma unroll
    for (int mi = 0; mi < 4; ++mi) {
      const int r = wm * 64 + mi * 16 + l15;
      const int rx = (r & 6) << 3;
      const char* p = (const char*)As[cur] + r * 64;
      union { uint2 u[2]; s16x8 v; } tmp;
      tmp.u[0] = *(const uint2*)(p + ((g4 << 3) ^ rx));
      tmp.u[1] = *(const uint2*)(p + (((g4 + 4) << 3) ^ rx));
      fa[mi] = tmp.v;
    }
#pragma unroll
    for (int ni = 0; ni < 2; ++ni) {
      const int r = wn * 32 + ni * 16 + l15;
      const int rx = (r & 6) << 3;
      const char* p = (const char*)Bs[cur] + r * 64;
      union { uint2 u[2]; s16x8 v; } tmp;
      tmp.u[0] = *(const uint2*)(p + ((g4 << 3) ^ rx));
      tmp.u[1] = *(const uint2*)(p + (((g4 + 4) << 3) ^ rx));
      fb[ni] = tmp.v;
    }
#pragma unroll
    for (int mi = 0; mi < 4; ++mi)
#pragma unroll
      for (int ni = 0; ni < 2; ++ni)
        acc[mi][ni] = __builtin_amdgcn_mfma_f32_16x16x32_bf16(
            fa[mi], fb[ni], acc[mi][ni], 0, 0, 0);
    asm volatile("s_waitcnt vmcnt(0)");
    __syncthreads();
    cur ^= 1;
  }
#undef G_STAGE
#pragma unroll
  for (int mi = 0; mi < 4; ++mi) {
    const int ob = o0 + wm * 64 + mi * 16 + g4 * 4;
#pragma unroll
    for (int ni = 0; ni < 2; ++ni) {
      const int n = bx * 64 + wn * 32 + ni * 16 + l15;
#pragma unroll
      for (int r = 0; r < 4; ++r) {
        const int oo = ob + r;
        T* dst = (oo < 256) ? O0 : (oo < 512) ? O1 : O2;
        dst[((size_t)b * CC + (oo & 255)) * NPIX + n] = (T)acc[mi][ni][r];
      }
    }
  }
}

// ---------------- GN stats from raw bf16 qkv: direct scale/shift ------------
__global__ __launch_bounds__(256) void qkvstat_kernel(
    const __bf16* __restrict__ qkv, const float* __restrict__ qgw,
    const float* __restrict__ qgb, const float* __restrict__ kgw,
    const float* __restrict__ kgb, const float* __restrict__ vgw,
    const float* __restrict__ vgb, float* __restrict__ sc,
    float* __restrict__ sh) {
  const int zg = blockIdx.x, b = blockIdx.y;
  const int t = threadIdx.x, w = t >> 6, ln = t & 63;
  __shared__ float Ss[8], Qs[8];
  __shared__ float st[2];
#pragma unroll
  for (int j = 0; j < 2; ++j) {
    const int ch = zg * 8 + w * 2 + j;
    const int z = ch >> 8, c = ch & 255;
    const __bf16* row =
        qkv + ((size_t)z * BB * CC + (size_t)b * CC + c) * NPIX;
    float S = 0.f, Q = 0.f;
    for (int i = ln; i < 392; i += 64) {
      union { uint4 u; __bf16 e[8]; } v;
      v.u = *(const uint4*)&row[i * 8];
#pragma unroll
      for (int e = 0; e < 8; ++e) {
        const float f = (float)v.e[e];
        S += f;
        Q += f * f;
      }
    }
#pragma unroll
    for (int off = 32; off > 0; off >>= 1) {
      S += __shfl_down(S, off);
      Q += __shfl_down(Q, off);
    }
    if (ln == 0) {
      Ss[w * 2 + j] = S;
      Qs[w * 2 + j] = Q;
    }
  }
  __syncthreads();
  if (t == 0) {
    float S = 0.f, Q = 0.f;
#pragma unroll
    for (int i = 0; i < 8; ++i) {
      S += Ss[i];
      Q += Qs[i];
    }
    const float m = S / 25088.f;
    const float var = Q / 25088.f - m * m;
    st[0] = m;
    st[1] = rsqrtf(var + 1e-5f);
  }
  __syncthreads();
  if (t < 8) {
    const int ch = zg * 8 + t;
    const int z = ch >> 8, c = ch & 255;
    const float gw = z == 0 ? qgw[c] : z == 1 ? kgw[c] : vgw[c];
    const float gb = z == 0 ? qgb[c] : z == 1 ? kgb[c] : vgb[c];
    const float s = gw * st[1];
    sc[(size_t)b * 768 + ch] = s;
    sh[(size_t)b * 768 + ch] = gb - st[0] * s;
  }
}

// ---------------- GroupNorm (final p-conv only) -----------------------------
__global__ __launch_bounds__(256) void gn_kernel(
    const float* __restrict__ in, const float* __restrict__ gw,
    const float* __restrict__ gb, float* __restrict__ out) {
  const int g = blockIdx.x, b = blockIdx.y;
  const float* p = in + ((size_t)b * CC + g * CPG) * NPIX;
  float* q = out + ((size_t)b * CC + g * CPG) * NPIX;
  const int tid = threadIdx.x;
  const int M4 = CPG * NPIX / 4;
  const float4* p4 = (const float4*)p;
  float4* q4 = (float4*)q;
  float4 r[25];
  float s = 0.f, ss = 0.f;
#pragma unroll
  for (int j = 0; j < 25; ++j) {
    const int i = tid + j * 256;
    if (i < M4) {
      const float4 v = p4[i];
      r[j] = v;
      s += v.x + v.y + v.z + v.w;
      ss += v.x * v.x + v.y * v.y + v.z * v.z + v.w * v.w;
    }
  }
#pragma unroll
  for (int off = 32; off > 0; off >>= 1) {
    s += __shfl_down(s, off);
    ss += __shfl_down(ss, off);
  }
  __shared__ float wsum[4], wsq[4], stat[2];
  const int wv = tid >> 6, lnn = tid & 63;
  if (lnn == 0) { wsum[wv] = s; wsq[wv] = ss; }
  __syncthreads();
  if (tid == 0) {
    float S = wsum[0] + wsum[1] + wsum[2] + wsum[3];
    float SS = wsq[0] + wsq[1] + wsq[2] + wsq[3];
    const float inv_m = 1.f / (CPG * NPIX);
    float mean = S * inv_m;
    float var = SS * inv_m - mean * mean;
    stat[0] = mean;
    stat[1] = rsqrtf(var + 1e-5f);
  }
  __syncthreads();
  const float mean = stat[0], inv = stat[1];
#pragma unroll
  for (int j = 0; j < 25; ++j) {
    const int i = tid + j * 256;
    if (i < M4) {
      const int ch = g * CPG + i / (NPIX / 4);
      const float w = gw[ch] * inv, bia = gb[ch];
      float4 v = r[j];
      v.x = (v.x - mean) * w + bia;
      v.y = (v.y - mean) * w + bia;
      v.z = (v.z - mean) * w + bia;
      v.w = (v.w - mean) * w + bia;
      q4[i] = v;
    }
  }
}

// ---------------- agent-token pool (raw bf16 q; affine after averaging) -----
__global__ __launch_bounds__(64) void pool_kernel(
    const __bf16* __restrict__ q, const float* __restrict__ sc,
    const float* __restrict__ sh, float* __restrict__ at) {
  const int bc = blockIdx.x;
  const int a = threadIdx.x;
  if (a >= AG) return;
  const int b = bc >> 8, c = bc & 255;
  const int py = a / 7, px = a % 7;
  const __bf16* p = q + (size_t)bc * NPIX + (py * 8) * HDIM + px * 8;
  float s = 0.f;
#pragma unroll
  for (int y = 0; y < 8; ++y)
#pragma unroll
    for (int x = 0; x < 8; ++x) s += (float)p[y * HDIM + x];
  at[(size_t)bc * AG + a] =
      s * (1.f / 64.f) * sc[(size_t)b * 768 + c] + sh[(size_t)b * 768 + c];
}

// ---------------- bias precompute -------------------------------------------
__device__ __forceinline__ float bilin7(const float* __restrict__ src, int y,
                                        int x) {
  float sy = fminf(fmaxf((y + 0.5f) * 0.125f - 0.5f, 0.f), 6.f);
  float sx = fminf(fmaxf((x + 0.5f) * 0.125f - 0.5f, 0.f), 6.f);
  int y0 = (int)sy, x0 = (int)sx;
  int y1 = min(y0 + 1, 6), x1 = min(x0 + 1, 6);
  float fy = sy - y0, fx = sx - x0;
  return (1.f - fy) * ((1.f - fx) * src[y0 * 7 + x0] + fx * src[y0 * 7 + x1]) +
         fy * ((1.f - fx) * src[y1 * 7 + x0] + fx * src[y1 * 7 + x1]);
}

// pbt[h][n][64-padded] (pad zeroed via memset)
__global__ __launch_bounds__(256) void bias1_kernel(
    const float* __restrict__ an, const float* __restrict__ ah,
    const float* __restrict__ aw, float* __restrict__ pbt) {
  const int ha = blockIdx.x;
  const int h = ha / AG, a = ha % AG;
  const float* src = an + (size_t)ha * 49;
  const float* ahp = ah + (size_t)ha * HDIM;
  const float* awp = aw + (size_t)ha * HDIM;
  for (int n = threadIdx.x; n < NPIX; n += 256) {
    const int y = n / HDIM, x = n % HDIM;
    pbt[((size_t)h * NPIX + n) * 64 + a] = bilin7(src, y, x) + ahp[y] + awp[x];
  }
}

// fill ab2 with -1e9 (pad agents -> exp()==0)
__global__ __launch_bounds__(256) void fill_kernel(float* __restrict__ p,
                                                   int n4) {
  const int i = blockIdx.x * 256 + threadIdx.x;
  if (i < n4) {
    float4 v = make_float4(-1e9f, -1e9f, -1e9f, -1e9f);
    *(float4*)&p[i * 4] = v;
  }
}

// ab2[h][n][64-padded]
__global__ __launch_bounds__(256) void bias2_kernel(
    const float* __restrict__ na, const float* __restrict__ hab,
    const float* __restrict__ wab, float* __restrict__ ab2) {
  const int ha = blockIdx.x;
  const int h = ha / AG, a = ha % AG;
  const float* src = na + (size_t)ha * 49;
  for (int n = threadIdx.x; n < NPIX; n += 256) {
    const int y = n / HDIM, x = n % HDIM;
    ab2[((size_t)h * NPIX + n) * 64 + a] =
        bilin7(src, y, x) + hab[((size_t)h * HDIM + y) * AG + a] +
        wab[((size_t)h * HDIM + x) * AG + a];
  }
}

// ---------------- pure transpose: bf16 [b][c][n] (head) -> bf16 [bh][n][32] -
__global__ __launch_bounds__(256) void tr_k_kernel(
    const __bf16* __restrict__ K, __bf16* __restrict__ Kt) {
  const int nt = blockIdx.x, h = blockIdx.y, b = blockIdx.z;
  const int n0 = nt * 64;
  __shared__ __bf16 T[32][72];
  const int t = threadIdx.x;
  {
    const int d = t >> 3, c8 = (t & 7) * 8;
    *(uint4*)&T[d][c8] =
        *(const uint4*)&K[((size_t)(b * CC + h * HD + d)) * NPIX + n0 + c8];
  }
  __syncthreads();
  {
    const int n = t >> 2, d0 = (t & 3) * 8;
    union { __bf16 e[8]; uint4 u; } buf;
#pragma unroll
    for (int j = 0; j < 8; ++j) buf.e[j] = T[d0 + j][n];
    *(uint4*)&Kt[((size_t)(b * NHEADS + h) * NPIX + n0 + n) * HD + d0] = buf.u;
  }
}

// ---------------- stage 1 (MFMA): GN affines folded -------------------------
__global__ __launch_bounds__(256) void stage1_kernel(
    const __bf16* __restrict__ Kt, const __bf16* __restrict__ V,
    const float* __restrict__ at, const float* __restrict__ pbt,
    const float* __restrict__ sc, const float* __restrict__ sh,
    float* __restrict__ av) {
  const int bh = blockIdx.x;
  const int b = bh >> 3, h = bh & 7;
  const int t = threadIdx.x;
  const int w = t >> 6, ln = t & 63;
  const int l15 = ln & 15, g4 = ln >> 4;

  __shared__ float atraw[64][33];
  __shared__ float sck_s[32], shk_s[32];
  __shared__ float cb_s[64];
  __shared__ __bf16 at_s[64][40];
  __shared__ __bf16 Es[4][64][40];
  __shared__ float avs[4][64][33];
  __shared__ float Ls[4][64];

  if (t < 32) {
    const size_t si = (size_t)b * 768 + 256 + h * HD + t;
    sck_s[t] = sc[si];
    shk_s[t] = sh[si];
  }
  for (int i = t; i < 64 * 32; i += 256) {
    const int d = i >> 6, a = i & 63;
    atraw[a][d] =
        (a < AG) ? at[((size_t)b * CC + h * HD + d) * AG + a] * SCALE : 0.f;
  }
  __syncthreads();
  if (t < 64) {
    float s = 0.f;
#pragma unroll
    for (int d = 0; d < HD; ++d) {
      const float v = atraw[t][d];
      s += v * shk_s[d];
      at_s[t][d] = (__bf16)(v * sck_s[d]);
    }
    cb_s[t] = s;
  }
  __syncthreads();

  s16x8 fa[4];
  float4 cbv[4];
#pragma unroll
  for (int mt = 0; mt < 4; ++mt) {
    fa[mt] = *(const s16x8*)&at_s[mt * 16 + l15][g4 * 8];
    cbv[mt] = *(const float4*)&cb_s[mt * 16 + g4 * 4];
  }

  const __bf16* Ktb = Kt + (size_t)bh * NPIX * HD;
  const __bf16* Vcb = V + ((size_t)b * CC + h * HD) * NPIX;
  const float* pbh = pbt + (size_t)h * NPIX * 64;

  const f32x4 zz = {0.f, 0.f, 0.f, 0.f};
  f32x4 avacc[4][2];
#pragma unroll
  for (int mt = 0; mt < 4; ++mt) {
    avacc[mt][0] = zz;
    avacc[mt][1] = zz;
  }
  float lsum[4][4] = {};

  for (int ct = w; ct < 98; ct += 4) {
    const int nc0 = ct * 32;
    f32x4 c0[4], c1[4];
    {
      const s16x8 kf0 =
          *(const s16x8*)&Ktb[(size_t)(nc0 + l15) * HD + g4 * 8];
      const s16x8 kf1 =
          *(const s16x8*)&Ktb[(size_t)(nc0 + 16 + l15) * HD + g4 * 8];
#pragma unroll
      for (int mt = 0; mt < 4; ++mt) {
        c0[mt] = __builtin_amdgcn_mfma_f32_16x16x32_bf16(fa[mt], kf0, zz, 0, 0, 0);
        c1[mt] = __builtin_amdgcn_mfma_f32_16x16x32_bf16(fa[mt], kf1, zz, 0, 0, 0);
      }
    }
#pragma unroll
    for (int mt = 0; mt < 4; ++mt) {
      const int a0 = mt * 16 + g4 * 4;
      {
        const float4 bi =
            *(const float4*)&pbh[(size_t)(nc0 + l15) * 64 + a0];
        const float e0 = __expf(c0[mt][0] + bi.x + cbv[mt].x);
        const float e1 = __expf(c0[mt][1] + bi.y + cbv[mt].y);
        const float e2 = __expf(c0[mt][2] + bi.z + cbv[mt].z);
        const float e3 = __expf(c0[mt][3] + bi.w + cbv[mt].w);
        lsum[mt][0] += e0; lsum[mt][1] += e1;
        lsum[mt][2] += e2; lsum[mt][3] += e3;
        Es[w][a0 + 0][l15] = (__bf16)e0;
        Es[w][a0 + 1][l15] = (__bf16)e1;
        Es[w][a0 + 2][l15] = (__bf16)e2;
        Es[w][a0 + 3][l15] = (__bf16)e3;
      }
      {
        const float4 bi =
            *(const float4*)&pbh[(size_t)(nc0 + 16 + l15) * 64 + a0];
        const float e0 = __expf(c1[mt][0] + bi.x + cbv[mt].x);
        const float e1 = __expf(c1[mt][1] + bi.y + cbv[mt].y);
        const float e2 = __expf(c1[mt][2] + bi.z + cbv[mt].z);
        const float e3 = __expf(c1[mt][3] + bi.w + cbv[mt].w);
        lsum[mt][0] += e0; lsum[mt][1] += e1;
        lsum[mt][2] += e2; lsum[mt][3] += e3;
        Es[w][a0 + 0][16 + l15] = (__bf16)e0;
        Es[w][a0 + 1][16 + l15] = (__bf16)e1;
        Es[w][a0 + 2][16 + l15] = (__bf16)e2;
        Es[w][a0 + 3][16 + l15] = (__bf16)e3;
      }
    }
    asm volatile("s_waitcnt lgkmcnt(0)" ::: "memory");
    const s16x8 vf0 =
        *(const s16x8*)&Vcb[(size_t)(l15) * NPIX + nc0 + g4 * 8];
    const s16x8 vf1 =
        *(const s16x8*)&Vcb[(size_t)(16 + l15) * NPIX + nc0 + g4 * 8];
#pragma unroll
    for (int mt = 0; mt < 4; ++mt) {
      const s16x8 ef = *(const s16x8*)&Es[w][mt * 16 + l15][g4 * 8];
      avacc[mt][0] =
          __builtin_amdgcn_mfma_f32_16x16x32_bf16(ef, vf0, avacc[mt][0], 0, 0, 0);
      avacc[mt][1] =
          __builtin_amdgcn_mfma_f32_16x16x32_bf16(ef, vf1, avacc[mt][1], 0, 0, 0);
    }
  }

#pragma unroll
  for (int mt = 0; mt < 4; ++mt)
#pragma unroll
    for (int r = 0; r < 4; ++r) {
      float v = lsum[mt][r];
      v += __shfl_xor(v, 1);
      v += __shfl_xor(v, 2);
      v += __shfl_xor(v, 4);
      v += __shfl_xor(v, 8);
      if (l15 == 0) Ls[w][mt * 16 + g4 * 4 + r] = v;
    }
#pragma unroll
  for (int mt = 0; mt < 4; ++mt)
#pragma unroll
    for (int dt = 0; dt < 2; ++dt)
#pragma unroll
      for (int r = 0; r < 4; ++r)
        avs[w][mt * 16 + g4 * 4 + r][dt * 16 + l15] = avacc[mt][dt][r];
  __syncthreads();
  for (int i = t; i < AG * HD; i += 256) {
    const int a = i >> 5, d = i & 31;
    const float L = Ls[0][a] + Ls[1][a] + Ls[2][a] + Ls[3][a];
    const float s = avs[0][a][d] + avs[1][a][d] + avs[2][a][d] + avs[3][a][d];
    const size_t si = (size_t)b * 768 + 512 + h * HD + d;
    av[((size_t)bh * AG + a) * HD + d] = (s / L) * sc[si] + sh[si];
  }
}

// ---------------- stage 2 (MFMA): Q affine folded into B-fragment -----------
__global__ __launch_bounds__(256) void stage2_kernel(
    const __bf16* __restrict__ Qt, const float* __restrict__ at,
    const float* __restrict__ av, const float* __restrict__ ab2,
    const float* __restrict__ sc, const float* __restrict__ sh,
    float* __restrict__ XO) {
  const int s = blockIdx.x;
  const int bh = blockIdx.y;
  const int b = bh >> 3, h = bh & 7;
  const int t = threadIdx.x;
  const int w = t >> 6, ln = t & 63;
  const int l15 = ln & 15, g4 = ln >> 4;

  __shared__ float atraw[64][33];
  __shared__ float scq_s[32], shq_s[32];
  __shared__ float cb2_s[64];
  __shared__ __bf16 atb[64][40];
  __shared__ __bf16 avbT[32][72];
  __shared__ __bf16 Es[4][16][72];
  __shared__ float Os[4][16][33];

  if (t < 32) {
    const size_t si = (size_t)b * 768 + h * HD + t;
    scq_s[t] = sc[si];
    shq_s[t] = sh[si];
  }
  for (int i = t; i < 64 * 32; i += 256) {
    const int d = i >> 6, a = i & 63;
    atraw[a][d] =
        (a < AG) ? at[((size_t)b * CC + h * HD + d) * AG + a] * SCALE : 0.f;
  }
  for (int i = t; i < 32 * 64; i += 256) {
    const int d = i >> 6, a = i & 63;
    const float v = (a < AG) ? av[((size_t)bh * AG + a) * HD + d] : 0.f;
    avbT[d][a] = (__bf16)v;
  }
  __syncthreads();
  if (t < 64) {
    float s2 = 0.f;
#pragma unroll
    for (int d = 0; d < HD; ++d) {
      const float v = atraw[t][d];
      s2 += v * shq_s[d];
      atb[t][d] = (__bf16)(v * scq_s[d]);
    }
    cb2_s[t] = s2;
  }
  __syncthreads();

  s16x8 at_fB[4];
  float q2b[4];
#pragma unroll
  for (int atile = 0; atile < 4; ++atile) {
    at_fB[atile] = *(const s16x8*)&atb[atile * 16 + l15][g4 * 8];
    q2b[atile] = cb2_s[atile * 16 + l15];
  }
  s16x8 av_fB[2][2];
#pragma unroll
  for (int dt = 0; dt < 2; ++dt)
#pragma unroll
    for (int ks = 0; ks < 2; ++ks)
      av_fB[dt][ks] = *(const s16x8*)&avbT[dt * 16 + l15][ks * 32 + g4 * 8];

  const __bf16* Qtb = Qt + (size_t)bh * NPIX * HD;
  const float* abh = ab2 + (size_t)h * NPIX * 64;
  float* Ob = XO + ((size_t)b * CC + h * HD) * NPIX;
  const f32x4 zz = {0.f, 0.f, 0.f, 0.f};
  const int nbase = s * 784;

  for (int ct = w; ct < 49; ct += 4) {
    const int n0 = nbase + ct * 16;
    const s16x8 qf = *(const s16x8*)&Qtb[(size_t)(n0 + l15) * HD + g4 * 8];
    f32x4 c[4];
#pragma unroll
    for (int atile = 0; atile < 4; ++atile)
      c[atile] = __builtin_amdgcn_mfma_f32_16x16x32_bf16(qf, at_fB[atile], zz, 0, 0, 0);
    float Lr[4];
#pragma unroll
    for (int r = 0; r < 4; ++r) {
      const int n = n0 + g4 * 4 + r;
      const float* brow = &abh[(size_t)n * 64];
      float es[4];
#pragma unroll
      for (int atile = 0; atile < 4; ++atile) {
        const float e = __expf(c[atile][r] + brow[atile * 16 + l15] + q2b[atile]);
        es[atile] = e;
        Es[w][g4 * 4 + r][atile * 16 + l15] = (__bf16)e;
      }
      float sr = (es[0] + es[1]) + (es[2] + es[3]);
      sr += __shfl_xor(sr, 1);
      sr += __shfl_xor(sr, 2);
      sr += __shfl_xor(sr, 4);
      sr += __shfl_xor(sr, 8);
      Lr[r] = sr;
    }
    asm volatile("s_waitcnt lgkmcnt(0)" ::: "memory");
    const s16x8 ef0 = *(const s16x8*)&Es[w][l15][g4 * 8];
    const s16x8 ef1 = *(const s16x8*)&Es[w][l15][32 + g4 * 8];
    f32x4 o0 = __builtin_amdgcn_mfma_f32_16x16x32_bf16(ef0, av_fB[0][0], zz, 0, 0, 0);
    o0 = __builtin_amdgcn_mfma_f32_16x16x32_bf16(ef1, av_fB[0][1], o0, 0, 0, 0);
    f32x4 o1 = __builtin_amdgcn_mfma_f32_16x16x32_bf16(ef0, av_fB[1][0], zz, 0, 0, 0);
    o1 = __builtin_amdgcn_mfma_f32_16x16x32_bf16(ef1, av_fB[1][1], o1, 0, 0, 0);
#pragma unroll
    for (int r = 0; r < 4; ++r) {
      const float inv = 1.f / Lr[r];
      Os[w][g4 * 4 + r][l15] = o0[r] * inv;
      Os[w][g4 * 4 + r][16 + l15] = o1[r] * inv;
    }
    asm volatile("s_waitcnt lgkmcnt(0)" ::: "memory");
#pragma unroll
    for (int it = 0; it < 8; ++it) {
      const int d = it * 4 + g4;
      Ob[(size_t)d * NPIX + n0 + l15] = Os[w][l15][d];
    }
  }
}

// ---------------- depthwise 3x3 conv, LDS-tiled, affine on bf16 load --------
__global__ __launch_bounds__(256) void dwconv_kernel(
    const __bf16* __restrict__ V, const float* __restrict__ sc,
    const float* __restrict__ sh, const float* __restrict__ w,
    const float* __restrict__ bias, float* __restrict__ XO) {
  const int bc = blockIdx.x;
  const int c = bc % CC;
  const int b = bc >> 8;
  const int tid = threadIdx.x;
  __shared__ float T[58][60];
  float* Tf = &T[0][0];
  for (int i = tid; i < 58 * 60; i += 256) Tf[i] = 0.f;
  __syncthreads();
  const size_t si = (size_t)b * 768 + 512 + c;
  const float scl = sc[si], shf = sh[si];
  const __bf16* src = V + (size_t)bc * NPIX;
  for (int i = tid; i < 392; i += 256) {
    const int y = i / 7, x8 = (i % 7) * 8;
    union { uint4 u; __bf16 e[8]; } raw;
    raw.u = *(const uint4*)&src[y * HDIM + x8];
#pragma unroll
    for (int j = 0; j < 8; ++j)
      T[y + 1][x8 + 1 + j] = (float)raw.e[j] * scl + shf;
  }
  __syncthreads();
  float k[9];
#pragma unroll
  for (int i = 0; i < 9; ++i) k[i] = w[c * 9 + i];
  const float bb = bias[c];
  float* dst = XO + (size_t)bc * NPIX;
  for (int n = tid; n < NPIX; n += 256) {
    const int y = n / HDIM, x = n % HDIM;
    const float s = bb +
        k[0] * T[y][x]     + k[1] * T[y][x + 1]     + k[2] * T[y][x + 2] +
        k[3] * T[y + 1][x] + k[4] * T[y + 1][x + 1] + k[5] * T[y + 1][x + 2] +
        k[6] * T[y + 2][x] + k[7] * T[y + 2][x + 1] + k[8] * T[y + 2][x + 2];
    dst[n] += s;
  }
}

// ---------------- host launch ------------------------------------------------
extern "C" void kernel_launch(void* const* d_in, const int* in_sizes, int n_in,
                              void* d_out, int out_size, void* d_ws,
                              size_t ws_size, hipStream_t stream) {
  const float* x     = (const float*)d_in[0];
  const float* q_w   = (const float*)d_in[1];
  const float* q_gw  = (const float*)d_in[2];
  const float* q_gb  = (const float*)d_in[3];
  const float* k_w   = (const float*)d_in[4];
  const float* k_gw  = (const float*)d_in[5];
  const float* k_gb  = (const float*)d_in[6];
  const float* v_w   = (const float*)d_in[7];
  const float* v_gw  = (const float*)d_in[8];
  const float* v_gb  = (const float*)d_in[9];
  const float* p_w   = (const float*)d_in[10];
  const float* p_gw  = (const float*)d_in[11];
  const float* p_gb  = (const float*)d_in[12];
  const float* dwc_w = (const float*)d_in[13];
  const float* dwc_b = (const float*)d_in[14];
  const float* an_b  = (const float*)d_in[15];
  const float* na_b  = (const float*)d_in[16];
  const float* ah_b  = (const float*)d_in[17];
  const float* aw_b  = (const float*)d_in[18];
  const float* ha_b  = (const float*)d_in[19];
  const float* wa_b  = (const float*)d_in[20];
  float* out = (float*)d_out;

  const size_t SZ_FEAT = (size_t)BB * CC * NPIX;       // 25,690,112 elements
  const size_t SZ_AT   = (size_t)BB * CC * AG;
  const size_t SZ_PBT  = (size_t)NHEADS * NPIX * 64;   // padded bias (x2)
  const size_t SZ_AV   = (size_t)BB * NHEADS * AG * HD;
  const size_t SZ_SC   = (size_t)BB * 768;             // GN scale/shift (x2)
  const size_t need =
      3 * SZ_FEAT * sizeof(__bf16) +
      (SZ_FEAT + SZ_AT + 2 * SZ_PBT + SZ_AV + 2 * SZ_SC) * sizeof(float) +
      1024 * 256 * sizeof(__bf16);
  if (ws_size < need) return;  // insufficient scratch: fail visibly

  __bf16* qbf = (__bf16*)d_ws;       // raw bf16 q from gemm (k,v contiguous)
  __bf16* kbf = qbf + SZ_FEAT;
  __bf16* vbf = kbf + SZ_FEAT;
  float* xo  = (float*)(vbf + SZ_FEAT);  // stage2 out + dwconv accum (fp32)
  float* at  = xo + SZ_FEAT;
  float* pbt = at + SZ_AT;
  float* ab2 = pbt + SZ_PBT;
  float* av  = ab2 + SZ_PBT;
  __bf16* wbf = (__bf16*)(av + SZ_AV);   // [1024][256]
  float* sc = (float*)(wbf + 1024 * 256);
  float* sh = sc + SZ_SC;

  // d_out scratch timeline: xbf front (QKV gemm input, dead after);
  // Kt back half -> Qt reuses after stage1; dead before final GN.
  __bf16* xbf = (__bf16*)d_out;
  __bf16* Kt  = (__bf16*)((char*)d_out + SZ_FEAT * 2);
  __bf16* Qt  = Kt;

  const dim3 ggrid(NGROUPS, BB);
  const dim3 tgrid(49, 4, BB);

  convert_w_kernel<<<dim3(256, 4), 256, 0, stream>>>(q_w, k_w, v_w, p_w, wbf);
  transpose_kernel<<<tgrid, 256, 0, stream>>>(x, xbf);
  gemm_kernel<__bf16><<<dim3(49, 6, BB), 256, 0, stream>>>(wbf, xbf, qbf, kbf,
                                                           vbf);
  qkvstat_kernel<<<dim3(96, BB), 256, 0, stream>>>(qbf, q_gw, q_gb, k_gw,
                                                   k_gb, v_gw, v_gb, sc, sh);

  pool_kernel<<<BB * CC, 64, 0, stream>>>(qbf, sc, sh, at);
  hipMemsetAsync(pbt, 0, SZ_PBT * sizeof(float), stream);
  bias1_kernel<<<NHEADS * AG, 256, 0, stream>>>(an_b, ah_b, aw_b, pbt);
  fill_kernel<<<(int)(SZ_PBT / 4 + 255) / 256, 256, 0, stream>>>(
      ab2, (int)(SZ_PBT / 4));
  bias2_kernel<<<NHEADS * AG, 256, 0, stream>>>(na_b, ha_b, wa_b, ab2);

  tr_k_kernel<<<dim3(49, NHEADS, BB), 256, 0, stream>>>(kbf, Kt);
  stage1_kernel<<<BB * NHEADS, 256, 0, stream>>>(Kt, vbf, at, pbt, sc, sh, av);

  tr_k_kernel<<<dim3(49, NHEADS, BB), 256, 0, stream>>>(qbf, Qt);
  stage2_kernel<<<dim3(4, BB * NHEADS), 256, 0, stream>>>(Qt, at, av, ab2, sc,
                                                          sh, xo);
  dwconv_kernel<<<BB * CC, 256, 0, stream>>>(vbf, sc, sh, dwc_w, dwc_b, xo);

  transpose_kernel<<<tgrid, 256, 0, stream>>>(xo, xbf);
  gemm_kernel<float><<<dim3(49, 2, BB), 256, 0, stream>>>(wbf + 768 * 256,
                                                          xbf, xo, xo, xo);
  gn_kernel<<<ggrid, 256, 0, stream>>>(xo, p_gw, p_gb, out);
}

// Round 21
// 448.762 us; speedup vs baseline: 1.4331x; 1.1129x over previous
//
#include <hip/hip_runtime.h>
#include <hip/hip_bf16.h>
#include <math.h>

#define BB      32
#define CC      256
#define HDIM    56
#define NPIX    3136
#define NHEADS  8
#define HD      32
#define AG      49
#define NGROUPS 32
#define CPG     8
#define SCALE   0.17677669529663687f

typedef short s16x8 __attribute__((ext_vector_type(8)));
typedef float f32x4 __attribute__((ext_vector_type(4)));
typedef unsigned int u32;

#define GLL16(g, l)                                                        \
  __builtin_amdgcn_global_load_lds(                                        \
      (const u32 __attribute__((address_space(1)))*)(g),                   \
      (u32 __attribute__((address_space(3)))*)(l), 16, 0, 0)

// ---------------- W convert: q/k/v/p fp32 (256x256) -> bf16 [1024][256] ----
__global__ __launch_bounds__(256) void convert_w_kernel(
    const float* __restrict__ q, const float* __restrict__ k,
    const float* __restrict__ v, const float* __restrict__ p,
    __bf16* __restrict__ w) {
  const int i = blockIdx.x * 256 + threadIdx.x;  // 0..65535
  const int z = blockIdx.y;
  const float* src = z == 0 ? q : z == 1 ? k : z == 2 ? v : p;
  w[(size_t)z * 65536 + i] = (__bf16)src[i];
}

// ---------------- transpose+convert: fp32 [b][c][n] -> bf16 [b*n][c] -------
__global__ __launch_bounds__(256) void transpose_kernel(
    const float* __restrict__ X, __bf16* __restrict__ Xt) {
  const int nt = blockIdx.x, ct = blockIdx.y, b = blockIdx.z;
  __shared__ __bf16 T[64][72];
  const int t = threadIdx.x;
  const int c0 = ct * 64, n0 = nt * 64;
  {
    const int c = t >> 2;
    const float* src = X + ((size_t)b * CC + c0 + c) * NPIX + n0;
#pragma unroll
    for (int j = 0; j < 4; ++j) {
      const int col = (t & 3) * 16 + j * 4;
      const float4 v = *(const float4*)&src[col];
      T[c][col + 0] = (__bf16)v.x;
      T[c][col + 1] = (__bf16)v.y;
      T[c][col + 2] = (__bf16)v.z;
      T[c][col + 3] = (__bf16)v.w;
    }
  }
  __syncthreads();
  {
    const int n = t >> 2;
    const int cl0 = (t & 3) * 16;
    __bf16* dst = Xt + ((size_t)b * NPIX + n0 + n) * CC + c0 + cl0;
    union { __bf16 e[16]; uint4 u[2]; } buf;
#pragma unroll
    for (int j = 0; j < 16; ++j) buf.e[j] = T[cl0 + j][n];
    *(uint4*)(dst + 0) = buf.u[0];
    *(uint4*)(dst + 8) = buf.u[1];
  }
}

// ---------------- transpose (bf16 in): [b][c][n] -> bf16 [b*n][c] ----------
__global__ __launch_bounds__(256) void transpose_b_kernel(
    const __bf16* __restrict__ X, __bf16* __restrict__ Xt) {
  const int nt = blockIdx.x, ct = blockIdx.y, b = blockIdx.z;
  __shared__ __bf16 T[64][72];
  const int t = threadIdx.x;
  const int c0 = ct * 64, n0 = nt * 64;
  {
    const int c = t >> 2;
    const __bf16* src = X + ((size_t)b * CC + c0 + c) * NPIX + n0;
    const int col = (t & 3) * 16;
    *(uint4*)&T[c][col + 0] = *(const uint4*)&src[col + 0];
    *(uint4*)&T[c][col + 8] = *(const uint4*)&src[col + 8];
  }
  __syncthreads();
  {
    const int n = t >> 2;
    const int cl0 = (t & 3) * 16;
    __bf16* dst = Xt + ((size_t)b * NPIX + n0 + n) * CC + c0 + cl0;
    union { __bf16 e[16]; uint4 u[2]; } buf;
#pragma unroll
    for (int j = 0; j < 16; ++j) buf.e[j] = T[cl0 + j][n];
    *(uint4*)(dst + 0) = buf.u[0];
    *(uint4*)(dst + 8) = buf.u[1];
  }
}

// ---------------- MFMA GEMM: LDS-staged, double-buffered --------------------
template <typename T>
__global__ __launch_bounds__(256) void gemm_kernel(
    const __bf16* __restrict__ W, const __bf16* __restrict__ Xt,
    T* __restrict__ O0, T* __restrict__ O1, T* __restrict__ O2) {
  __shared__ __bf16 As[2][128 * 32];
  __shared__ __bf16 Bs[2][64 * 32];
  const int bx = blockIdx.x;
  const int by = blockIdx.y;
  const int b = blockIdx.z;
  const int t = threadIdx.x;
  const int o0 = by * 128;

  const int ar0 = t >> 2, G = t & 3;
  const int sa0 = G ^ ((ar0 >> 1) & 3);
  const int ar1 = 64 + ar0;
  const int sa1 = G ^ ((ar1 >> 1) & 3);
  const char* wbase = (const char*)W;
  const char* xbase = (const char*)(Xt + ((size_t)b * NPIX + bx * 64) * CC);
  const size_t ga0 = (size_t)(o0 + ar0) * 512 + sa0 * 16;
  const size_t ga1 = (size_t)(o0 + ar1) * 512 + sa1 * 16;
  const size_t gb0 = (size_t)ar0 * 512 + sa0 * 16;

  const int wv = t >> 6, ln = t & 63;
  const int wm = wv >> 1, wn = wv & 1;
  const int l15 = ln & 15, g4 = ln >> 4;

#define G_STAGE(buf, k0)                                                   \
  {                                                                        \
    GLL16(wbase + ga0 + (k0) * 2, (char*)As[buf] + t * 16);                \
    GLL16(wbase + ga1 + (k0) * 2, (char*)As[buf] + 4096 + t * 16);         \
    GLL16(xbase + gb0 + (k0) * 2, (char*)Bs[buf] + t * 16);                \
  }

  const f32x4 zz = {0.f, 0.f, 0.f, 0.f};
  f32x4 acc[4][2];
#pragma unroll
  for (int mi = 0; mi < 4; ++mi)
#pragma unroll
    for (int ni = 0; ni < 2; ++ni) acc[mi][ni] = zz;

  G_STAGE(0, 0);
  asm volatile("s_waitcnt vmcnt(0)");
  __syncthreads();

  int cur = 0;
#pragma unroll
  for (int k0 = 0; k0 < 256; k0 += 32) {
    if (k0 < 224) G_STAGE(cur ^ 1, k0 + 32);
    s16x8 fa[4], fb[2];
#pragma unroll
    for (int mi = 0; mi < 4; ++mi) {
      const int r = wm * 64 + mi * 16 + l15;
      const int rx = (r & 6) << 3;
      const char* p = (const char*)As[cur] + r * 64;
      union { uint2 u[2]; s16x8 v; } tmp;
      tmp.u[0] = *(const uint2*)(p + ((g4 << 3) ^ rx));
      tmp.u[1] = *(const uint2*)(p + (((g4 + 4) << 3) ^ rx));
      fa[mi] = tmp.v;
    }
#pragma unroll
    for (int ni = 0; ni < 2; ++ni) {
      const int r = wn * 32 + ni * 16 + l15;
      const int rx = (r & 6) << 3;
      const char* p = (const char*)Bs[cur] + r * 64;
      union { uint2 u[2]; s16x8 v; } tmp;
      tmp.u[0] = *(const uint2*)(p + ((g4 << 3) ^ rx));
      tmp.u[1] = *(const uint2*)(p + (((g4 + 4) << 3) ^ rx));
      fb[ni] = tmp.v;
    }
#pragma unroll
    for (int mi = 0; mi < 4; ++mi)
#pragma unroll
      for (int ni = 0; ni < 2; ++ni)
        acc[mi][ni] = __builtin_amdgcn_mfma_f32_16x16x32_bf16(
            fa[mi], fb[ni], acc[mi][ni], 0, 0, 0);
    asm volatile("s_waitcnt vmcnt(0)");
    __syncthreads();
    cur ^= 1;
  }
#undef G_STAGE
#pragma unroll
  for (int mi = 0; mi < 4; ++mi) {
    const int ob = o0 + wm * 64 + mi * 16 + g4 * 4;
#pragma unroll
    for (int ni = 0; ni < 2; ++ni) {
      const int n = bx * 64 + wn * 32 + ni * 16 + l15;
#pragma unroll
      for (int r = 0; r < 4; ++r) {
        const int oo = ob + r;
        T* dst = (oo < 256) ? O0 : (oo < 512) ? O1 : O2;
        dst[((size_t)b * CC + (oo & 255)) * NPIX + n] = (T)acc[mi][ni][r];
      }
    }
  }
}

// ---------------- GN stats from raw bf16 qkv: direct scale/shift ------------
__global__ __launch_bounds__(256) void qkvstat_kernel(
    const __bf16* __restrict__ qkv, const float* __restrict__ qgw,
    const float* __restrict__ qgb, const float* __restrict__ kgw,
    const float* __restrict__ kgb, const float* __restrict__ vgw,
    const float* __restrict__ vgb, float* __restrict__ sc,
    float* __restrict__ sh) {
  const int zg = blockIdx.x, b = blockIdx.y;
  const int t = threadIdx.x, w = t >> 6, ln = t & 63;
  __shared__ float Ss[8], Qs[8];
  __shared__ float st[2];
#pragma unroll
  for (int j = 0; j < 2; ++j) {
    const int ch = zg * 8 + w * 2 + j;
    const int z = ch >> 8, c = ch & 255;
    const __bf16* row =
        qkv + ((size_t)z * BB * CC + (size_t)b * CC + c) * NPIX;
    float S = 0.f, Q = 0.f;
    for (int i = ln; i < 392; i += 64) {
      union { uint4 u; __bf16 e[8]; } v;
      v.u = *(const uint4*)&row[i * 8];
#pragma unroll
      for (int e = 0; e < 8; ++e) {
        const float f = (float)v.e[e];
        S += f;
        Q += f * f;
      }
    }
#pragma unroll
    for (int off = 32; off > 0; off >>= 1) {
      S += __shfl_down(S, off);
      Q += __shfl_down(Q, off);
    }
    if (ln == 0) {
      Ss[w * 2 + j] = S;
      Qs[w * 2 + j] = Q;
    }
  }
  __syncthreads();
  if (t == 0) {
    float S = 0.f, Q = 0.f;
#pragma unroll
    for (int i = 0; i < 8; ++i) {
      S += Ss[i];
      Q += Qs[i];
    }
    const float m = S / 25088.f;
    const float var = Q / 25088.f - m * m;
    st[0] = m;
    st[1] = rsqrtf(var + 1e-5f);
  }
  __syncthreads();
  if (t < 8) {
    const int ch = zg * 8 + t;
    const int z = ch >> 8, c = ch & 255;
    const float gw = z == 0 ? qgw[c] : z == 1 ? kgw[c] : vgw[c];
    const float gb = z == 0 ? qgb[c] : z == 1 ? kgb[c] : vgb[c];
    const float s = gw * st[1];
    sc[(size_t)b * 768 + ch] = s;
    sh[(size_t)b * 768 + ch] = gb - st[0] * s;
  }
}

// ---------------- GroupNorm, bf16 input -> fp32 out (final p-conv) ----------
__global__ __launch_bounds__(256) void gn_kernel(
    const __bf16* __restrict__ in, const float* __restrict__ gw,
    const float* __restrict__ gb, float* __restrict__ out) {
  const int g = blockIdx.x, b = blockIdx.y;
  const __bf16* p = in + ((size_t)b * CC + g * CPG) * NPIX;
  float* q = out + ((size_t)b * CC + g * CPG) * NPIX;
  const int tid = threadIdx.x;
  const int M8 = CPG * NPIX / 8;  // 3136 uint4 chunks
  union { uint4 u; __bf16 e[8]; } r[13];
  float s = 0.f, ss = 0.f;
#pragma unroll
  for (int j = 0; j < 13; ++j) {
    const int i = tid + j * 256;
    if (i < M8) {
      r[j].u = *(const uint4*)&p[i * 8];
#pragma unroll
      for (int e = 0; e < 8; ++e) {
        const float f = (float)r[j].e[e];
        s += f;
        ss += f * f;
      }
    }
  }
#pragma unroll
  for (int off = 32; off > 0; off >>= 1) {
    s += __shfl_down(s, off);
    ss += __shfl_down(ss, off);
  }
  __shared__ float wsum[4], wsq[4], stat[2];
  const int wv = tid >> 6, lnn = tid & 63;
  if (lnn == 0) { wsum[wv] = s; wsq[wv] = ss; }
  __syncthreads();
  if (tid == 0) {
    float S = wsum[0] + wsum[1] + wsum[2] + wsum[3];
    float SS = wsq[0] + wsq[1] + wsq[2] + wsq[3];
    const float inv_m = 1.f / (CPG * NPIX);
    float mean = S * inv_m;
    float var = SS * inv_m - mean * mean;
    stat[0] = mean;
    stat[1] = rsqrtf(var + 1e-5f);
  }
  __syncthreads();
  const float mean = stat[0], inv = stat[1];
#pragma unroll
  for (int j = 0; j < 13; ++j) {
    const int i = tid + j * 256;
    if (i < M8) {
      const int ch = g * CPG + i / (NPIX / 8);
      const float w = gw[ch] * inv, bia = gb[ch];
      float4 o0, o1;
      o0.x = ((float)r[j].e[0] - mean) * w + bia;
      o0.y = ((float)r[j].e[1] - mean) * w + bia;
      o0.z = ((float)r[j].e[2] - mean) * w + bia;
      o0.w = ((float)r[j].e[3] - mean) * w + bia;
      o1.x = ((float)r[j].e[4] - mean) * w + bia;
      o1.y = ((float)r[j].e[5] - mean) * w + bia;
      o1.z = ((float)r[j].e[6] - mean) * w + bia;
      o1.w = ((float)r[j].e[7] - mean) * w + bia;
      *(float4*)&q[i * 8 + 0] = o0;
      *(float4*)&q[i * 8 + 4] = o1;
    }
  }
}

// ---------------- agent-token pool (raw bf16 q; affine after averaging) -----
__global__ __launch_bounds__(64) void pool_kernel(
    const __bf16* __restrict__ q, const float* __restrict__ sc,
    const float* __restrict__ sh, float* __restrict__ at) {
  const int bc = blockIdx.x;
  const int a = threadIdx.x;
  if (a >= AG) return;
  const int b = bc >> 8, c = bc & 255;
  const int py = a / 7, px = a % 7;
  const __bf16* p = q + (size_t)bc * NPIX + (py * 8) * HDIM + px * 8;
  float s = 0.f;
#pragma unroll
  for (int y = 0; y < 8; ++y)
#pragma unroll
    for (int x = 0; x < 8; ++x) s += (float)p[y * HDIM + x];
  at[(size_t)bc * AG + a] =
      s * (1.f / 64.f) * sc[(size_t)b * 768 + c] + sh[(size_t)b * 768 + c];
}

// ---------------- bias precompute -------------------------------------------
__device__ __forceinline__ float bilin7(const float* __restrict__ src, int y,
                                        int x) {
  float sy = fminf(fmaxf((y + 0.5f) * 0.125f - 0.5f, 0.f), 6.f);
  float sx = fminf(fmaxf((x + 0.5f) * 0.125f - 0.5f, 0.f), 6.f);
  int y0 = (int)sy, x0 = (int)sx;
  int y1 = min(y0 + 1, 6), x1 = min(x0 + 1, 6);
  float fy = sy - y0, fx = sx - x0;
  return (1.f - fy) * ((1.f - fx) * src[y0 * 7 + x0] + fx * src[y0 * 7 + x1]) +
         fy * ((1.f - fx) * src[y1 * 7 + x0] + fx * src[y1 * 7 + x1]);
}

// pbt[h][n][64-padded] (pad zeroed via memset)
__global__ __launch_bounds__(256) void bias1_kernel(
    const float* __restrict__ an, const float* __restrict__ ah,
    const float* __restrict__ aw, float* __restrict__ pbt) {
  const int ha = blockIdx.x;
  const int h = ha / AG, a = ha % AG;
  const float* src = an + (size_t)ha * 49;
  const float* ahp = ah + (size_t)ha * HDIM;
  const float* awp = aw + (size_t)ha * HDIM;
  for (int n = threadIdx.x; n < NPIX; n += 256) {
    const int y = n / HDIM, x = n % HDIM;
    pbt[((size_t)h * NPIX + n) * 64 + a] = bilin7(src, y, x) + ahp[y] + awp[x];
  }
}

// fill ab2 with -1e9 (pad agents -> exp()==0)
__global__ __launch_bounds__(256) void fill_kernel(float* __restrict__ p,
                                                   int n4) {
  const int i = blockIdx.x * 256 + threadIdx.x;
  if (i < n4) {
    float4 v = make_float4(-1e9f, -1e9f, -1e9f, -1e9f);
    *(float4*)&p[i * 4] = v;
  }
}

// ab2[h][n][64-padded]
__global__ __launch_bounds__(256) void bias2_kernel(
    const float* __restrict__ na, const float* __restrict__ hab,
    const float* __restrict__ wab, float* __restrict__ ab2) {
  const int ha = blockIdx.x;
  const int h = ha / AG, a = ha % AG;
  const float* src = na + (size_t)ha * 49;
  for (int n = threadIdx.x; n < NPIX; n += 256) {
    const int y = n / HDIM, x = n % HDIM;
    ab2[((size_t)h * NPIX + n) * 64 + a] =
        bilin7(src, y, x) + hab[((size_t)h * HDIM + y) * AG + a] +
        wab[((size_t)h * HDIM + x) * AG + a];
  }
}

// ---------------- pure transpose: bf16 [b][c][n] (head) -> bf16 [bh][n][32] -
__global__ __launch_bounds__(256) void tr_k_kernel(
    const __bf16* __restrict__ K, __bf16* __restrict__ Kt) {
  const int nt = blockIdx.x, h = blockIdx.y, b = blockIdx.z;
  const int n0 = nt * 64;
  __shared__ __bf16 T[32][72];
  const int t = threadIdx.x;
  {
    const int d = t >> 3, c8 = (t & 7) * 8;
    *(uint4*)&T[d][c8] =
        *(const uint4*)&K[((size_t)(b * CC + h * HD + d)) * NPIX + n0 + c8];
  }
  __syncthreads();
  {
    const int n = t >> 2, d0 = (t & 3) * 8;
    union { __bf16 e[8]; uint4 u; } buf;
#pragma unroll
    for (int j = 0; j < 8; ++j) buf.e[j] = T[d0 + j][n];
    *(uint4*)&Kt[((size_t)(b * NHEADS + h) * NPIX + n0 + n) * HD + d0] = buf.u;
  }
}

// ---------------- stage 1 (MFMA): GN affines folded -------------------------
__global__ __launch_bounds__(256) void stage1_kernel(
    const __bf16* __restrict__ Kt, const __bf16* __restrict__ V,
    const float* __restrict__ at, const float* __restrict__ pbt,
    const float* __restrict__ sc, const float* __restrict__ sh,
    float* __restrict__ av) {
  const int bh = blockIdx.x;
  const int b = bh >> 3, h = bh & 7;
  const int t = threadIdx.x;
  const int w = t >> 6, ln = t & 63;
  const int l15 = ln & 15, g4 = ln >> 4;

  __shared__ float atraw[64][33];
  __shared__ float sck_s[32], shk_s[32];
  __shared__ float cb_s[64];
  __shared__ __bf16 at_s[64][40];
  __shared__ __bf16 Es[4][64][40];
  __shared__ float avs[4][64][33];
  __shared__ float Ls[4][64];

  if (t < 32) {
    const size_t si = (size_t)b * 768 + 256 + h * HD + t;
    sck_s[t] = sc[si];
    shk_s[t] = sh[si];
  }
  for (int i = t; i < 64 * 32; i += 256) {
    const int d = i >> 6, a = i & 63;
    atraw[a][d] =
        (a < AG) ? at[((size_t)b * CC + h * HD + d) * AG + a] * SCALE : 0.f;
  }
  __syncthreads();
  if (t < 64) {
    float s = 0.f;
#pragma unroll
    for (int d = 0; d < HD; ++d) {
      const float v = atraw[t][d];
      s += v * shk_s[d];
      at_s[t][d] = (__bf16)(v * sck_s[d]);
    }
    cb_s[t] = s;
  }
  __syncthreads();

  s16x8 fa[4];
  float4 cbv[4];
#pragma unroll
  for (int mt = 0; mt < 4; ++mt) {
    fa[mt] = *(const s16x8*)&at_s[mt * 16 + l15][g4 * 8];
    cbv[mt] = *(const float4*)&cb_s[mt * 16 + g4 * 4];
  }

  const __bf16* Ktb = Kt + (size_t)bh * NPIX * HD;
  const __bf16* Vcb = V + ((size_t)b * CC + h * HD) * NPIX;
  const float* pbh = pbt + (size_t)h * NPIX * 64;

  const f32x4 zz = {0.f, 0.f, 0.f, 0.f};
  f32x4 avacc[4][2];
#pragma unroll
  for (int mt = 0; mt < 4; ++mt) {
    avacc[mt][0] = zz;
    avacc[mt][1] = zz;
  }
  float lsum[4][4] = {};

  for (int ct = w; ct < 98; ct += 4) {
    const int nc0 = ct * 32;
    f32x4 c0[4], c1[4];
    {
      const s16x8 kf0 =
          *(const s16x8*)&Ktb[(size_t)(nc0 + l15) * HD + g4 * 8];
      const s16x8 kf1 =
          *(const s16x8*)&Ktb[(size_t)(nc0 + 16 + l15) * HD + g4 * 8];
#pragma unroll
      for (int mt = 0; mt < 4; ++mt) {
        c0[mt] = __builtin_amdgcn_mfma_f32_16x16x32_bf16(fa[mt], kf0, zz, 0, 0, 0);
        c1[mt] = __builtin_amdgcn_mfma_f32_16x16x32_bf16(fa[mt], kf1, zz, 0, 0, 0);
      }
    }
#pragma unroll
    for (int mt = 0; mt < 4; ++mt) {
      const int a0 = mt * 16 + g4 * 4;
      {
        const float4 bi =
            *(const float4*)&pbh[(size_t)(nc0 + l15) * 64 + a0];
        const float e0 = __expf(c0[mt][0] + bi.x + cbv[mt].x);
        const float e1 = __expf(c0[mt][1] + bi.y + cbv[mt].y);
        const float e2 = __expf(c0[mt][2] + bi.z + cbv[mt].z);
        const float e3 = __expf(c0[mt][3] + bi.w + cbv[mt].w);
        lsum[mt][0] += e0; lsum[mt][1] += e1;
        lsum[mt][2] += e2; lsum[mt][3] += e3;
        Es[w][a0 + 0][l15] = (__bf16)e0;
        Es[w][a0 + 1][l15] = (__bf16)e1;
        Es[w][a0 + 2][l15] = (__bf16)e2;
        Es[w][a0 + 3][l15] = (__bf16)e3;
      }
      {
        const float4 bi =
            *(const float4*)&pbh[(size_t)(nc0 + 16 + l15) * 64 + a0];
        const float e0 = __expf(c1[mt][0] + bi.x + cbv[mt].x);
        const float e1 = __expf(c1[mt][1] + bi.y + cbv[mt].y);
        const float e2 = __expf(c1[mt][2] + bi.z + cbv[mt].z);
        const float e3 = __expf(c1[mt][3] + bi.w + cbv[mt].w);
        lsum[mt][0] += e0; lsum[mt][1] += e1;
        lsum[mt][2] += e2; lsum[mt][3] += e3;
        Es[w][a0 + 0][16 + l15] = (__bf16)e0;
        Es[w][a0 + 1][16 + l15] = (__bf16)e1;
        Es[w][a0 + 2][16 + l15] = (__bf16)e2;
        Es[w][a0 + 3][16 + l15] = (__bf16)e3;
      }
    }
    asm volatile("s_waitcnt lgkmcnt(0)" ::: "memory");
    const s16x8 vf0 =
        *(const s16x8*)&Vcb[(size_t)(l15) * NPIX + nc0 + g4 * 8];
    const s16x8 vf1 =
        *(const s16x8*)&Vcb[(size_t)(16 + l15) * NPIX + nc0 + g4 * 8];
#pragma unroll
    for (int mt = 0; mt < 4; ++mt) {
      const s16x8 ef = *(const s16x8*)&Es[w][mt * 16 + l15][g4 * 8];
      avacc[mt][0] =
          __builtin_amdgcn_mfma_f32_16x16x32_bf16(ef, vf0, avacc[mt][0], 0, 0, 0);
      avacc[mt][1] =
          __builtin_amdgcn_mfma_f32_16x16x32_bf16(ef, vf1, avacc[mt][1], 0, 0, 0);
    }
  }

#pragma unroll
  for (int mt = 0; mt < 4; ++mt)
#pragma unroll
    for (int r = 0; r < 4; ++r) {
      float v = lsum[mt][r];
      v += __shfl_xor(v, 1);
      v += __shfl_xor(v, 2);
      v += __shfl_xor(v, 4);
      v += __shfl_xor(v, 8);
      if (l15 == 0) Ls[w][mt * 16 + g4 * 4 + r] = v;
    }
#pragma unroll
  for (int mt = 0; mt < 4; ++mt)
#pragma unroll
    for (int dt = 0; dt < 2; ++dt)
#pragma unroll
      for (int r = 0; r < 4; ++r)
        avs[w][mt * 16 + g4 * 4 + r][dt * 16 + l15] = avacc[mt][dt][r];
  __syncthreads();
  for (int i = t; i < AG * HD; i += 256) {
    const int a = i >> 5, d = i & 31;
    const float L = Ls[0][a] + Ls[1][a] + Ls[2][a] + Ls[3][a];
    const float s = avs[0][a][d] + avs[1][a][d] + avs[2][a][d] + avs[3][a][d];
    const size_t si = (size_t)b * 768 + 512 + h * HD + d;
    av[((size_t)bh * AG + a) * HD + d] = (s / L) * sc[si] + sh[si];
  }
}

// ---------------- stage 2 (MFMA): Q affine folded; bf16 output --------------
__global__ __launch_bounds__(256) void stage2_kernel(
    const __bf16* __restrict__ Qt, const float* __restrict__ at,
    const float* __restrict__ av, const float* __restrict__ ab2,
    const float* __restrict__ sc, const float* __restrict__ sh,
    __bf16* __restrict__ XO) {
  const int s = blockIdx.x;
  const int bh = blockIdx.y;
  const int b = bh >> 3, h = bh & 7;
  const int t = threadIdx.x;
  const int w = t >> 6, ln = t & 63;
  const int l15 = ln & 15, g4 = ln >> 4;

  __shared__ float atraw[64][33];
  __shared__ float scq_s[32], shq_s[32];
  __shared__ float cb2_s[64];
  __shared__ __bf16 atb[64][40];
  __shared__ __bf16 avbT[32][72];
  __shared__ __bf16 Es[4][16][72];
  __shared__ float Os[4][16][33];

  if (t < 32) {
    const size_t si = (size_t)b * 768 + h * HD + t;
    scq_s[t] = sc[si];
    shq_s[t] = sh[si];
  }
  for (int i = t; i < 64 * 32; i += 256) {
    const int d = i >> 6, a = i & 63;
    atraw[a][d] =
        (a < AG) ? at[((size_t)b * CC + h * HD + d) * AG + a] * SCALE : 0.f;
  }
  for (int i = t; i < 32 * 64; i += 256) {
    const int d = i >> 6, a = i & 63;
    const float v = (a < AG) ? av[((size_t)bh * AG + a) * HD + d] : 0.f;
    avbT[d][a] = (__bf16)v;
  }
  __syncthreads();
  if (t < 64) {
    float s2 = 0.f;
#pragma unroll
    for (int d = 0; d < HD; ++d) {
      const float v = atraw[t][d];
      s2 += v * shq_s[d];
      atb[t][d] = (__bf16)(v * scq_s[d]);
    }
    cb2_s[t] = s2;
  }
  __syncthreads();

  s16x8 at_fB[4];
  float q2b[4];
#pragma unroll
  for (int atile = 0; atile < 4; ++atile) {
    at_fB[atile] = *(const s16x8*)&atb[atile * 16 + l15][g4 * 8];
    q2b[atile] = cb2_s[atile * 16 + l15];
  }
  s16x8 av_fB[2][2];
#pragma unroll
  for (int dt = 0; dt < 2; ++dt)
#pragma unroll
    for (int ks = 0; ks < 2; ++ks)
      av_fB[dt][ks] = *(const s16x8*)&avbT[dt * 16 + l15][ks * 32 + g4 * 8];

  const __bf16* Qtb = Qt + (size_t)bh * NPIX * HD;
  const float* abh = ab2 + (size_t)h * NPIX * 64;
  __bf16* Ob = XO + ((size_t)b * CC + h * HD) * NPIX;
  const f32x4 zz = {0.f, 0.f, 0.f, 0.f};
  const int nbase = s * 784;

  for (int ct = w; ct < 49; ct += 4) {
    const int n0 = nbase + ct * 16;
    const s16x8 qf = *(const s16x8*)&Qtb[(size_t)(n0 + l15) * HD + g4 * 8];
    f32x4 c[4];
#pragma unroll
    for (int atile = 0; atile < 4; ++atile)
      c[atile] = __builtin_amdgcn_mfma_f32_16x16x32_bf16(qf, at_fB[atile], zz, 0, 0, 0);
    float Lr[4];
#pragma unroll
    for (int r = 0; r < 4; ++r) {
      const int n = n0 + g4 * 4 + r;
      const float* brow = &abh[(size_t)n * 64];
      float es[4];
#pragma unroll
      for (int atile = 0; atile < 4; ++atile) {
        const float e = __expf(c[atile][r] + brow[atile * 16 + l15] + q2b[atile]);
        es[atile] = e;
        Es[w][g4 * 4 + r][atile * 16 + l15] = (__bf16)e;
      }
      float sr = (es[0] + es[1]) + (es[2] + es[3]);
      sr += __shfl_xor(sr, 1);
      sr += __shfl_xor(sr, 2);
      sr += __shfl_xor(sr, 4);
      sr += __shfl_xor(sr, 8);
      Lr[r] = sr;
    }
    asm volatile("s_waitcnt lgkmcnt(0)" ::: "memory");
    const s16x8 ef0 = *(const s16x8*)&Es[w][l15][g4 * 8];
    const s16x8 ef1 = *(const s16x8*)&Es[w][l15][32 + g4 * 8];
    f32x4 o0 = __builtin_amdgcn_mfma_f32_16x16x32_bf16(ef0, av_fB[0][0], zz, 0, 0, 0);
    o0 = __builtin_amdgcn_mfma_f32_16x16x32_bf16(ef1, av_fB[0][1], o0, 0, 0, 0);
    f32x4 o1 = __builtin_amdgcn_mfma_f32_16x16x32_bf16(ef0, av_fB[1][0], zz, 0, 0, 0);
    o1 = __builtin_amdgcn_mfma_f32_16x16x32_bf16(ef1, av_fB[1][1], o1, 0, 0, 0);
#pragma unroll
    for (int r = 0; r < 4; ++r) {
      const float inv = 1.f / Lr[r];
      Os[w][g4 * 4 + r][l15] = o0[r] * inv;
      Os[w][g4 * 4 + r][16 + l15] = o1[r] * inv;
    }
    asm volatile("s_waitcnt lgkmcnt(0)" ::: "memory");
#pragma unroll
    for (int it = 0; it < 8; ++it) {
      const int d = it * 4 + g4;
      Ob[(size_t)d * NPIX + n0 + l15] = (__bf16)Os[w][l15][d];
    }
  }
}

// ---------------- depthwise 3x3 conv, LDS-tiled, bf16 RMW into XO -----------
__global__ __launch_bounds__(256) void dwconv_kernel(
    const __bf16* __restrict__ V, const float* __restrict__ sc,
    const float* __restrict__ sh, const float* __restrict__ w,
    const float* __restrict__ bias, __bf16* __restrict__ XO) {
  const int bc = blockIdx.x;
  const int c = bc % CC;
  const int b = bc >> 8;
  const int tid = threadIdx.x;
  __shared__ float T[58][60];
  float* Tf = &T[0][0];
  for (int i = tid; i < 58 * 60; i += 256) Tf[i] = 0.f;
  __syncthreads();
  const size_t si = (size_t)b * 768 + 512 + c;
  const float scl = sc[si], shf = sh[si];
  const __bf16* src = V + (size_t)bc * NPIX;
  for (int i = tid; i < 392; i += 256) {
    const int y = i / 7, x8 = (i % 7) * 8;
    union { uint4 u; __bf16 e[8]; } raw;
    raw.u = *(const uint4*)&src[y * HDIM + x8];
#pragma unroll
    for (int j = 0; j < 8; ++j)
      T[y + 1][x8 + 1 + j] = (float)raw.e[j] * scl + shf;
  }
  __syncthreads();
  float k[9];
#pragma unroll
  for (int i = 0; i < 9; ++i) k[i] = w[c * 9 + i];
  const float bb = bias[c];
  __bf16* dst = XO + (size_t)bc * NPIX;
  for (int n = tid; n < NPIX; n += 256) {
    const int y = n / HDIM, x = n % HDIM;
    const float s = bb +
        k[0] * T[y][x]     + k[1] * T[y][x + 1]     + k[2] * T[y][x + 2] +
        k[3] * T[y + 1][x] + k[4] * T[y + 1][x + 1] + k[5] * T[y + 1][x + 2] +
        k[6] * T[y + 2][x] + k[7] * T[y + 2][x + 1] + k[8] * T[y + 2][x + 2];
    dst[n] = (__bf16)((float)dst[n] + s);
  }
}

// ---------------- host launch ------------------------------------------------
extern "C" void kernel_launch(void* const* d_in, const int* in_sizes, int n_in,
                              void* d_out, int out_size, void* d_ws,
                              size_t ws_size, hipStream_t stream) {
  const float* x     = (const float*)d_in[0];
  const float* q_w   = (const float*)d_in[1];
  const float* q_gw  = (const float*)d_in[2];
  const float* q_gb  = (const float*)d_in[3];
  const float* k_w   = (const float*)d_in[4];
  const float* k_gw  = (const float*)d_in[5];
  const float* k_gb  = (const float*)d_in[6];
  const float* v_w   = (const float*)d_in[7];
  const float* v_gw  = (const float*)d_in[8];
  const float* v_gb  = (const float*)d_in[9];
  const float* p_w   = (const float*)d_in[10];
  const float* p_gw  = (const float*)d_in[11];
  const float* p_gb  = (const float*)d_in[12];
  const float* dwc_w = (const float*)d_in[13];
  const float* dwc_b = (const float*)d_in[14];
  const float* an_b  = (const float*)d_in[15];
  const float* na_b  = (const float*)d_in[16];
  const float* ah_b  = (const float*)d_in[17];
  const float* aw_b  = (const float*)d_in[18];
  const float* ha_b  = (const float*)d_in[19];
  const float* wa_b  = (const float*)d_in[20];
  float* out = (float*)d_out;

  const size_t SZ_FEAT = (size_t)BB * CC * NPIX;       // 25,690,112 elements
  const size_t SZ_AT   = (size_t)BB * CC * AG;
  const size_t SZ_PBT  = (size_t)NHEADS * NPIX * 64;   // padded bias (x2)
  const size_t SZ_AV   = (size_t)BB * NHEADS * AG * HD;
  const size_t SZ_SC   = (size_t)BB * 768;             // GN scale/shift (x2)
  const size_t need =
      4 * SZ_FEAT * sizeof(__bf16) +
      (SZ_AT + 2 * SZ_PBT + SZ_AV + 2 * SZ_SC) * sizeof(float) +
      1024 * 256 * sizeof(__bf16);
  if (ws_size < need) return;  // insufficient scratch: fail visibly

  __bf16* qbf = (__bf16*)d_ws;       // raw bf16 q from gemm (k,v contiguous)
  __bf16* kbf = qbf + SZ_FEAT;
  __bf16* vbf = kbf + SZ_FEAT;
  __bf16* xo  = vbf + SZ_FEAT;       // stage2 out + dwconv RMW (bf16);
  __bf16* pob = xo;                  // p-gemm bf16 out reuses xo (dead then)
  float* at  = (float*)(xo + SZ_FEAT);
  float* pbt = at + SZ_AT;
  float* ab2 = pbt + SZ_PBT;
  float* av  = ab2 + SZ_PBT;
  __bf16* wbf = (__bf16*)(av + SZ_AV);   // [1024][256]
  float* sc = (float*)(wbf + 1024 * 256);
  float* sh = sc + SZ_SC;

  // d_out scratch timeline: xbf front (gemm input); Kt back half -> Qt
  // reuses after stage1; all dead before final gn writes d_out.
  __bf16* xbf = (__bf16*)d_out;
  __bf16* Kt  = (__bf16*)((char*)d_out + SZ_FEAT * 2);
  __bf16* Qt  = Kt;

  const dim3 ggrid(NGROUPS, BB);
  const dim3 tgrid(49, 4, BB);

  convert_w_kernel<<<dim3(256, 4), 256, 0, stream>>>(q_w, k_w, v_w, p_w, wbf);
  transpose_kernel<<<tgrid, 256, 0, stream>>>(x, xbf);
  gemm_kernel<__bf16><<<dim3(49, 6, BB), 256, 0, stream>>>(wbf, xbf, qbf, kbf,
                                                           vbf);
  qkvstat_kernel<<<dim3(96, BB), 256, 0, stream>>>(qbf, q_gw, q_gb, k_gw,
                                                   k_gb, v_gw, v_gb, sc, sh);

  pool_kernel<<<BB * CC, 64, 0, stream>>>(qbf, sc, sh, at);
  hipMemsetAsync(pbt, 0, SZ_PBT * sizeof(float), stream);
  bias1_kernel<<<NHEADS * AG, 256, 0, stream>>>(an_b, ah_b, aw_b, pbt);
  fill_kernel<<<(int)(SZ_PBT / 4 + 255) / 256, 256, 0, stream>>>(
      ab2, (int)(SZ_PBT / 4));
  bias2_kernel<<<NHEADS * AG, 256, 0, stream>>>(na_b, ha_b, wa_b, ab2);

  tr_k_kernel<<<dim3(49, NHEADS, BB), 256, 0, stream>>>(kbf, Kt);
  stage1_kernel<<<BB * NHEADS, 256, 0, stream>>>(Kt, vbf, at, pbt, sc, sh, av);

  tr_k_kernel<<<dim3(49, NHEADS, BB), 256, 0, stream>>>(qbf, Qt);
  stage2_kernel<<<dim3(4, BB * NHEADS), 256, 0, stream>>>(Qt, at, av, ab2, sc,
                                                          sh, xo);
  dwconv_kernel<<<BB * CC, 256, 0, stream>>>(vbf, sc, sh, dwc_w, dwc_b, xo);

  transpose_b_kernel<<<tgrid, 256, 0, stream>>>(xo, xbf);
  gemm_kernel<__bf16><<<dim3(49, 2, BB), 256, 0, stream>>>(wbf + 768 * 256,
                                                           xbf, pob, pob, pob);
  gn_kernel<<<ggrid, 256, 0, stream>>>(pob, p_gw, p_gb, out);
}

// Round 22
// 432.051 us; speedup vs baseline: 1.4886x; 1.0387x over previous
//
#include <hip/hip_runtime.h>
#include <hip/hip_bf16.h>
#include <math.h>

#define BB      32
#define CC      256
#define HDIM    56
#define NPIX    3136
#define NHEADS  8
#define HD      32
#define AG      49
#define NGROUPS 32
#define CPG     8
#define SCALE   0.17677669529663687f

typedef short s16x8 __attribute__((ext_vector_type(8)));
typedef float f32x4 __attribute__((ext_vector_type(4)));
typedef unsigned int u32;

#define GLL16(g, l)                                                        \
  __builtin_amdgcn_global_load_lds(                                        \
      (const u32 __attribute__((address_space(1)))*)(g),                   \
      (u32 __attribute__((address_space(3)))*)(l), 16, 0, 0)

// ---------------- W convert: q/k/v/p fp32 (256x256) -> bf16 [1024][256] ----
__global__ __launch_bounds__(256) void convert_w_kernel(
    const float* __restrict__ q, const float* __restrict__ k,
    const float* __restrict__ v, const float* __restrict__ p,
    __bf16* __restrict__ w) {
  const int i = blockIdx.x * 256 + threadIdx.x;  // 0..65535
  const int z = blockIdx.y;
  const float* src = z == 0 ? q : z == 1 ? k : z == 2 ? v : p;
  w[(size_t)z * 65536 + i] = (__bf16)src[i];
}

// ---------------- transpose+convert: fp32 [b][c][n] -> bf16 [b*n][c] -------
__global__ __launch_bounds__(256) void transpose_kernel(
    const float* __restrict__ X, __bf16* __restrict__ Xt) {
  const int nt = blockIdx.x, ct = blockIdx.y, b = blockIdx.z;
  __shared__ __bf16 T[64][72];
  const int t = threadIdx.x;
  const int c0 = ct * 64, n0 = nt * 64;
  {
    const int c = t >> 2;
    const float* src = X + ((size_t)b * CC + c0 + c) * NPIX + n0;
#pragma unroll
    for (int j = 0; j < 4; ++j) {
      const int col = (t & 3) * 16 + j * 4;
      const float4 v = *(const float4*)&src[col];
      T[c][col + 0] = (__bf16)v.x;
      T[c][col + 1] = (__bf16)v.y;
      T[c][col + 2] = (__bf16)v.z;
      T[c][col + 3] = (__bf16)v.w;
    }
  }
  __syncthreads();
  {
    const int n = t >> 2;
    const int cl0 = (t & 3) * 16;
    __bf16* dst = Xt + ((size_t)b * NPIX + n0 + n) * CC + c0 + cl0;
    union { __bf16 e[16]; uint4 u[2]; } buf;
#pragma unroll
    for (int j = 0; j < 16; ++j) buf.e[j] = T[cl0 + j][n];
    *(uint4*)(dst + 0) = buf.u[0];
    *(uint4*)(dst + 8) = buf.u[1];
  }
}

// ---------------- transpose (bf16 in): [b][c][n] -> bf16 [b*n][c] ----------
__global__ __launch_bounds__(256) void transpose_b_kernel(
    const __bf16* __restrict__ X, __bf16* __restrict__ Xt) {
  const int nt = blockIdx.x, ct = blockIdx.y, b = blockIdx.z;
  __shared__ __bf16 T[64][72];
  const int t = threadIdx.x;
  const int c0 = ct * 64, n0 = nt * 64;
  {
    const int c = t >> 2;
    const __bf16* src = X + ((size_t)b * CC + c0 + c) * NPIX + n0;
    const int col = (t & 3) * 16;
    *(uint4*)&T[c][col + 0] = *(const uint4*)&src[col + 0];
    *(uint4*)&T[c][col + 8] = *(const uint4*)&src[col + 8];
  }
  __syncthreads();
  {
    const int n = t >> 2;
    const int cl0 = (t & 3) * 16;
    __bf16* dst = Xt + ((size_t)b * NPIX + n0 + n) * CC + c0 + cl0;
    union { __bf16 e[16]; uint4 u[2]; } buf;
#pragma unroll
    for (int j = 0; j < 16; ++j) buf.e[j] = T[cl0 + j][n];
    *(uint4*)(dst + 0) = buf.u[0];
    *(uint4*)(dst + 8) = buf.u[1];
  }
}

// ---------------- MFMA GEMM: LDS-staged, double-buffered --------------------
// Round-22: grid is (by, bx, b) -- the 6 by-blocks sharing one Xt tile are
// dispatch-consecutive so L2/L3 absorb the re-reads (FETCH was 3x unique).
template <typename T>
__global__ __launch_bounds__(256) void gemm_kernel(
    const __bf16* __restrict__ W, const __bf16* __restrict__ Xt,
    T* __restrict__ O0, T* __restrict__ O1, T* __restrict__ O2) {
  __shared__ __bf16 As[2][128 * 32];
  __shared__ __bf16 Bs[2][64 * 32];
  const int bx = blockIdx.y;
  const int by = blockIdx.x;
  const int b = blockIdx.z;
  const int t = threadIdx.x;
  const int o0 = by * 128;

  const int ar0 = t >> 2, G = t & 3;
  const int sa0 = G ^ ((ar0 >> 1) & 3);
  const int ar1 = 64 + ar0;
  const int sa1 = G ^ ((ar1 >> 1) & 3);
  const char* wbase = (const char*)W;
  const char* xbase = (const char*)(Xt + ((size_t)b * NPIX + bx * 64) * CC);
  const size_t ga0 = (size_t)(o0 + ar0) * 512 + sa0 * 16;
  const size_t ga1 = (size_t)(o0 + ar1) * 512 + sa1 * 16;
  const size_t gb0 = (size_t)ar0 * 512 + sa0 * 16;

  const int wv = t >> 6, ln = t & 63;
  const int wm = wv >> 1, wn = wv & 1;
  const int l15 = ln & 15, g4 = ln >> 4;

#define G_STAGE(buf, k0)                                                   \
  {                                                                        \
    GLL16(wbase + ga0 + (k0) * 2, (char*)As[buf] + t * 16);                \
    GLL16(wbase + ga1 + (k0) * 2, (char*)As[buf] + 4096 + t * 16);         \
    GLL16(xbase + gb0 + (k0) * 2, (char*)Bs[buf] + t * 16);                \
  }

  const f32x4 zz = {0.f, 0.f, 0.f, 0.f};
  f32x4 acc[4][2];
#pragma unroll
  for (int mi = 0; mi < 4; ++mi)
#pragma unroll
    for (int ni = 0; ni < 2; ++ni) acc[mi][ni] = zz;

  G_STAGE(0, 0);
  asm volatile("s_waitcnt vmcnt(0)");
  __syncthreads();

  int cur = 0;
#pragma unroll
  for (int k0 = 0; k0 < 256; k0 += 32) {
    if (k0 < 224) G_STAGE(cur ^ 1, k0 + 32);
    s16x8 fa[4], fb[2];
#pragma unroll
    for (int mi = 0; mi < 4; ++mi) {
      const int r = wm * 64 + mi * 16 + l15;
      const int rx = (r & 6) << 3;
      const char* p = (const char*)As[cur] + r * 64;
      union { uint2 u[2]; s16x8 v; } tmp;
      tmp.u[0] = *(const uint2*)(p + ((g4 << 3) ^ rx));
      tmp.u[1] = *(const uint2*)(p + (((g4 + 4) << 3) ^ rx));
      fa[mi] = tmp.v;
    }
#pragma unroll
    for (int ni = 0; ni < 2; ++ni) {
      const int r = wn * 32 + ni * 16 + l15;
      const int rx = (r & 6) << 3;
      const char* p = (const char*)Bs[cur] + r * 64;
      union { uint2 u[2]; s16x8 v; } tmp;
      tmp.u[0] = *(const uint2*)(p + ((g4 << 3) ^ rx));
      tmp.u[1] = *(const uint2*)(p + (((g4 + 4) << 3) ^ rx));
      fb[ni] = tmp.v;
    }
#pragma unroll
    for (int mi = 0; mi < 4; ++mi)
#pragma unroll
      for (int ni = 0; ni < 2; ++ni)
        acc[mi][ni] = __builtin_amdgcn_mfma_f32_16x16x32_bf16(
            fa[mi], fb[ni], acc[mi][ni], 0, 0, 0);
    asm volatile("s_waitcnt vmcnt(0)");
    __syncthreads();
    cur ^= 1;
  }
#undef G_STAGE
#pragma unroll
  for (int mi = 0; mi < 4; ++mi) {
    const int ob = o0 + wm * 64 + mi * 16 + g4 * 4;
#pragma unroll
    for (int ni = 0; ni < 2; ++ni) {
      const int n = bx * 64 + wn * 32 + ni * 16 + l15;
#pragma unroll
      for (int r = 0; r < 4; ++r) {
        const int oo = ob + r;
        T* dst = (oo < 256) ? O0 : (oo < 512) ? O1 : O2;
        dst[((size_t)b * CC + (oo & 255)) * NPIX + n] = (T)acc[mi][ni][r];
      }
    }
  }
}

// ---------------- GN stats from raw bf16 qkv: direct scale/shift ------------
__global__ __launch_bounds__(256) void qkvstat_kernel(
    const __bf16* __restrict__ qkv, const float* __restrict__ qgw,
    const float* __restrict__ qgb, const float* __restrict__ kgw,
    const float* __restrict__ kgb, const float* __restrict__ vgw,
    const float* __restrict__ vgb, float* __restrict__ sc,
    float* __restrict__ sh) {
  const int zg = blockIdx.x, b = blockIdx.y;
  const int t = threadIdx.x, w = t >> 6, ln = t & 63;
  __shared__ float Ss[8], Qs[8];
  __shared__ float st[2];
#pragma unroll
  for (int j = 0; j < 2; ++j) {
    const int ch = zg * 8 + w * 2 + j;
    const int z = ch >> 8, c = ch & 255;
    const __bf16* row =
        qkv + ((size_t)z * BB * CC + (size_t)b * CC + c) * NPIX;
    float S = 0.f, Q = 0.f;
    for (int i = ln; i < 392; i += 64) {
      union { uint4 u; __bf16 e[8]; } v;
      v.u = *(const uint4*)&row[i * 8];
#pragma unroll
      for (int e = 0; e < 8; ++e) {
        const float f = (float)v.e[e];
        S += f;
        Q += f * f;
      }
    }
#pragma unroll
    for (int off = 32; off > 0; off >>= 1) {
      S += __shfl_down(S, off);
      Q += __shfl_down(Q, off);
    }
    if (ln == 0) {
      Ss[w * 2 + j] = S;
      Qs[w * 2 + j] = Q;
    }
  }
  __syncthreads();
  if (t == 0) {
    float S = 0.f, Q = 0.f;
#pragma unroll
    for (int i = 0; i < 8; ++i) {
      S += Ss[i];
      Q += Qs[i];
    }
    const float m = S / 25088.f;
    const float var = Q / 25088.f - m * m;
    st[0] = m;
    st[1] = rsqrtf(var + 1e-5f);
  }
  __syncthreads();
  if (t < 8) {
    const int ch = zg * 8 + t;
    const int z = ch >> 8, c = ch & 255;
    const float gw = z == 0 ? qgw[c] : z == 1 ? kgw[c] : vgw[c];
    const float gb = z == 0 ? qgb[c] : z == 1 ? kgb[c] : vgb[c];
    const float s = gw * st[1];
    sc[(size_t)b * 768 + ch] = s;
    sh[(size_t)b * 768 + ch] = gb - st[0] * s;
  }
}

// ---------------- GroupNorm, bf16 input -> fp32 out (final p-conv) ----------
__global__ __launch_bounds__(256) void gn_kernel(
    const __bf16* __restrict__ in, const float* __restrict__ gw,
    const float* __restrict__ gb, float* __restrict__ out) {
  const int g = blockIdx.x, b = blockIdx.y;
  const __bf16* p = in + ((size_t)b * CC + g * CPG) * NPIX;
  float* q = out + ((size_t)b * CC + g * CPG) * NPIX;
  const int tid = threadIdx.x;
  const int M8 = CPG * NPIX / 8;  // 3136 uint4 chunks
  union { uint4 u; __bf16 e[8]; } r[13];
  float s = 0.f, ss = 0.f;
#pragma unroll
  for (int j = 0; j < 13; ++j) {
    const int i = tid + j * 256;
    if (i < M8) {
      r[j].u = *(const uint4*)&p[i * 8];
#pragma unroll
      for (int e = 0; e < 8; ++e) {
        const float f = (float)r[j].e[e];
        s += f;
        ss += f * f;
      }
    }
  }
#pragma unroll
  for (int off = 32; off > 0; off >>= 1) {
    s += __shfl_down(s, off);
    ss += __shfl_down(ss, off);
  }
  __shared__ float wsum[4], wsq[4], stat[2];
  const int wv = tid >> 6, lnn = tid & 63;
  if (lnn == 0) { wsum[wv] = s; wsq[wv] = ss; }
  __syncthreads();
  if (tid == 0) {
    float S = wsum[0] + wsum[1] + wsum[2] + wsum[3];
    float SS = wsq[0] + wsq[1] + wsq[2] + wsq[3];
    const float inv_m = 1.f / (CPG * NPIX);
    float mean = S * inv_m;
    float var = SS * inv_m - mean * mean;
    stat[0] = mean;
    stat[1] = rsqrtf(var + 1e-5f);
  }
  __syncthreads();
  const float mean = stat[0], inv = stat[1];
#pragma unroll
  for (int j = 0; j < 13; ++j) {
    const int i = tid + j * 256;
    if (i < M8) {
      const int ch = g * CPG + i / (NPIX / 8);
      const float w = gw[ch] * inv, bia = gb[ch];
      float4 o0, o1;
      o0.x = ((float)r[j].e[0] - mean) * w + bia;
      o0.y = ((float)r[j].e[1] - mean) * w + bia;
      o0.z = ((float)r[j].e[2] - mean) * w + bia;
      o0.w = ((float)r[j].e[3] - mean) * w + bia;
      o1.x = ((float)r[j].e[4] - mean) * w + bia;
      o1.y = ((float)r[j].e[5] - mean) * w + bia;
      o1.z = ((float)r[j].e[6] - mean) * w + bia;
      o1.w = ((float)r[j].e[7] - mean) * w + bia;
      *(float4*)&q[i * 8 + 0] = o0;
      *(float4*)&q[i * 8 + 4] = o1;
    }
  }
}

// ---------------- agent-token pool (raw bf16 q; affine after averaging) -----
__global__ __launch_bounds__(64) void pool_kernel(
    const __bf16* __restrict__ q, const float* __restrict__ sc,
    const float* __restrict__ sh, float* __restrict__ at) {
  const int bc = blockIdx.x;
  const int a = threadIdx.x;
  if (a >= AG) return;
  const int b = bc >> 8, c = bc & 255;
  const int py = a / 7, px = a % 7;
  const __bf16* p = q + (size_t)bc * NPIX + (py * 8) * HDIM + px * 8;
  float s = 0.f;
#pragma unroll
  for (int y = 0; y < 8; ++y)
#pragma unroll
    for (int x = 0; x < 8; ++x) s += (float)p[y * HDIM + x];
  at[(size_t)bc * AG + a] =
      s * (1.f / 64.f) * sc[(size_t)b * 768 + c] + sh[(size_t)b * 768 + c];
}

// ---------------- bias precompute -------------------------------------------
__device__ __forceinline__ float bilin7(const float* __restrict__ src, int y,
                                        int x) {
  float sy = fminf(fmaxf((y + 0.5f) * 0.125f - 0.5f, 0.f), 6.f);
  float sx = fminf(fmaxf((x + 0.5f) * 0.125f - 0.5f, 0.f), 6.f);
  int y0 = (int)sy, x0 = (int)sx;
  int y1 = min(y0 + 1, 6), x1 = min(x0 + 1, 6);
  float fy = sy - y0, fx = sx - x0;
  return (1.f - fy) * ((1.f - fx) * src[y0 * 7 + x0] + fx * src[y0 * 7 + x1]) +
         fy * ((1.f - fx) * src[y1 * 7 + x0] + fx * src[y1 * 7 + x1]);
}

// pbt[h][n][64-padded] bf16 (pad zeroed via memset)
__global__ __launch_bounds__(256) void bias1_kernel(
    const float* __restrict__ an, const float* __restrict__ ah,
    const float* __restrict__ aw, __bf16* __restrict__ pbt) {
  const int ha = blockIdx.x;
  const int h = ha / AG, a = ha % AG;
  const float* src = an + (size_t)ha * 49;
  const float* ahp = ah + (size_t)ha * HDIM;
  const float* awp = aw + (size_t)ha * HDIM;
  for (int n = threadIdx.x; n < NPIX; n += 256) {
    const int y = n / HDIM, x = n % HDIM;
    pbt[((size_t)h * NPIX + n) * 64 + a] =
        (__bf16)(bilin7(src, y, x) + ahp[y] + awp[x]);
  }
}

// fill ab2 with bf16(-1e9) pattern (pad agents -> exp()==0)
__global__ __launch_bounds__(256) void fill_kernel(__bf16* __restrict__ p,
                                                   int n8) {
  const int i = blockIdx.x * 256 + threadIdx.x;
  if (i < n8) {
    uint4 v;
    v.x = v.y = v.z = v.w = 0xCE6ECE6Eu;  // bf16 -9.97e8 x2
    *(uint4*)&p[i * 8] = v;
  }
}

// ab2[h][n][64-padded] bf16
__global__ __launch_bounds__(256) void bias2_kernel(
    const float* __restrict__ na, const float* __restrict__ hab,
    const float* __restrict__ wab, __bf16* __restrict__ ab2) {
  const int ha = blockIdx.x;
  const int h = ha / AG, a = ha % AG;
  const float* src = na + (size_t)ha * 49;
  for (int n = threadIdx.x; n < NPIX; n += 256) {
    const int y = n / HDIM, x = n % HDIM;
    ab2[((size_t)h * NPIX + n) * 64 + a] =
        (__bf16)(bilin7(src, y, x) + hab[((size_t)h * HDIM + y) * AG + a] +
                 wab[((size_t)h * HDIM + x) * AG + a]);
  }
}

// ---------------- pure transpose: bf16 [b][c][n] (head) -> bf16 [bh][n][32] -
__global__ __launch_bounds__(256) void tr_k_kernel(
    const __bf16* __restrict__ K, __bf16* __restrict__ Kt) {
  const int nt = blockIdx.x, h = blockIdx.y, b = blockIdx.z;
  const int n0 = nt * 64;
  __shared__ __bf16 T[32][72];
  const int t = threadIdx.x;
  {
    const int d = t >> 3, c8 = (t & 7) * 8;
    *(uint4*)&T[d][c8] =
        *(const uint4*)&K[((size_t)(b * CC + h * HD + d)) * NPIX + n0 + c8];
  }
  __syncthreads();
  {
    const int n = t >> 2, d0 = (t & 3) * 8;
    union { __bf16 e[8]; uint4 u; } buf;
#pragma unroll
    for (int j = 0; j < 8; ++j) buf.e[j] = T[d0 + j][n];
    *(uint4*)&Kt[((size_t)(b * NHEADS + h) * NPIX + n0 + n) * HD + d0] = buf.u;
  }
}

// ---------------- stage 1 (MFMA): GN affines folded; bf16 bias --------------
__global__ __launch_bounds__(256) void stage1_kernel(
    const __bf16* __restrict__ Kt, const __bf16* __restrict__ V,
    const float* __restrict__ at, const __bf16* __restrict__ pbt,
    const float* __restrict__ sc, const float* __restrict__ sh,
    float* __restrict__ av) {
  const int bh = blockIdx.x;
  const int b = bh >> 3, h = bh & 7;
  const int t = threadIdx.x;
  const int w = t >> 6, ln = t & 63;
  const int l15 = ln & 15, g4 = ln >> 4;

  __shared__ float atraw[64][33];
  __shared__ float sck_s[32], shk_s[32];
  __shared__ float cb_s[64];
  __shared__ __bf16 at_s[64][40];
  __shared__ __bf16 Es[4][64][40];
  __shared__ float avs[4][64][33];
  __shared__ float Ls[4][64];

  if (t < 32) {
    const size_t si = (size_t)b * 768 + 256 + h * HD + t;
    sck_s[t] = sc[si];
    shk_s[t] = sh[si];
  }
  for (int i = t; i < 64 * 32; i += 256) {
    const int d = i >> 6, a = i & 63;
    atraw[a][d] =
        (a < AG) ? at[((size_t)b * CC + h * HD + d) * AG + a] * SCALE : 0.f;
  }
  __syncthreads();
  if (t < 64) {
    float s = 0.f;
#pragma unroll
    for (int d = 0; d < HD; ++d) {
      const float v = atraw[t][d];
      s += v * shk_s[d];
      at_s[t][d] = (__bf16)(v * sck_s[d]);
    }
    cb_s[t] = s;
  }
  __syncthreads();

  s16x8 fa[4];
  float4 cbv[4];
#pragma unroll
  for (int mt = 0; mt < 4; ++mt) {
    fa[mt] = *(const s16x8*)&at_s[mt * 16 + l15][g4 * 8];
    cbv[mt] = *(const float4*)&cb_s[mt * 16 + g4 * 4];
  }

  const __bf16* Ktb = Kt + (size_t)bh * NPIX * HD;
  const __bf16* Vcb = V + ((size_t)b * CC + h * HD) * NPIX;
  const __bf16* pbh = pbt + (size_t)h * NPIX * 64;

  const f32x4 zz = {0.f, 0.f, 0.f, 0.f};
  f32x4 avacc[4][2];
#pragma unroll
  for (int mt = 0; mt < 4; ++mt) {
    avacc[mt][0] = zz;
    avacc[mt][1] = zz;
  }
  float lsum[4][4] = {};

  for (int ct = w; ct < 98; ct += 4) {
    const int nc0 = ct * 32;
    f32x4 c0[4], c1[4];
    {
      const s16x8 kf0 =
          *(const s16x8*)&Ktb[(size_t)(nc0 + l15) * HD + g4 * 8];
      const s16x8 kf1 =
          *(const s16x8*)&Ktb[(size_t)(nc0 + 16 + l15) * HD + g4 * 8];
#pragma unroll
      for (int mt = 0; mt < 4; ++mt) {
        c0[mt] = __builtin_amdgcn_mfma_f32_16x16x32_bf16(fa[mt], kf0, zz, 0, 0, 0);
        c1[mt] = __builtin_amdgcn_mfma_f32_16x16x32_bf16(fa[mt], kf1, zz, 0, 0, 0);
      }
    }
#pragma unroll
    for (int mt = 0; mt < 4; ++mt) {
      const int a0 = mt * 16 + g4 * 4;
      {
        union { ushort4 u; __bf16 e[4]; } bi;
        bi.u = *(const ushort4*)&pbh[(size_t)(nc0 + l15) * 64 + a0];
        const float e0 = __expf(c0[mt][0] + (float)bi.e[0] + cbv[mt].x);
        const float e1 = __expf(c0[mt][1] + (float)bi.e[1] + cbv[mt].y);
        const float e2 = __expf(c0[mt][2] + (float)bi.e[2] + cbv[mt].z);
        const float e3 = __expf(c0[mt][3] + (float)bi.e[3] + cbv[mt].w);
        lsum[mt][0] += e0; lsum[mt][1] += e1;
        lsum[mt][2] += e2; lsum[mt][3] += e3;
        Es[w][a0 + 0][l15] = (__bf16)e0;
        Es[w][a0 + 1][l15] = (__bf16)e1;
        Es[w][a0 + 2][l15] = (__bf16)e2;
        Es[w][a0 + 3][l15] = (__bf16)e3;
      }
      {
        union { ushort4 u; __bf16 e[4]; } bi;
        bi.u = *(const ushort4*)&pbh[(size_t)(nc0 + 16 + l15) * 64 + a0];
        const float e0 = __expf(c1[mt][0] + (float)bi.e[0] + cbv[mt].x);
        const float e1 = __expf(c1[mt][1] + (float)bi.e[1] + cbv[mt].y);
        const float e2 = __expf(c1[mt][2] + (float)bi.e[2] + cbv[mt].z);
        const float e3 = __expf(c1[mt][3] + (float)bi.e[3] + cbv[mt].w);
        lsum[mt][0] += e0; lsum[mt][1] += e1;
        lsum[mt][2] += e2; lsum[mt][3] += e3;
        Es[w][a0 + 0][16 + l15] = (__bf16)e0;
        Es[w][a0 + 1][16 + l15] = (__bf16)e1;
        Es[w][a0 + 2][16 + l15] = (__bf16)e2;
        Es[w][a0 + 3][16 + l15] = (__bf16)e3;
      }
    }
    asm volatile("s_waitcnt lgkmcnt(0)" ::: "memory");
    const s16x8 vf0 =
        *(const s16x8*)&Vcb[(size_t)(l15) * NPIX + nc0 + g4 * 8];
    const s16x8 vf1 =
        *(const s16x8*)&Vcb[(size_t)(16 + l15) * NPIX + nc0 + g4 * 8];
#pragma unroll
    for (int mt = 0; mt < 4; ++mt) {
      const s16x8 ef = *(const s16x8*)&Es[w][mt * 16 + l15][g4 * 8];
      avacc[mt][0] =
          __builtin_amdgcn_mfma_f32_16x16x32_bf16(ef, vf0, avacc[mt][0], 0, 0, 0);
      avacc[mt][1] =
          __builtin_amdgcn_mfma_f32_16x16x32_bf16(ef, vf1, avacc[mt][1], 0, 0, 0);
    }
  }

#pragma unroll
  for (int mt = 0; mt < 4; ++mt)
#pragma unroll
    for (int r = 0; r < 4; ++r) {
      float v = lsum[mt][r];
      v += __shfl_xor(v, 1);
      v += __shfl_xor(v, 2);
      v += __shfl_xor(v, 4);
      v += __shfl_xor(v, 8);
      if (l15 == 0) Ls[w][mt * 16 + g4 * 4 + r] = v;
    }
#pragma unroll
  for (int mt = 0; mt < 4; ++mt)
#pragma unroll
    for (int dt = 0; dt < 2; ++dt)
#pragma unroll
      for (int r = 0; r < 4; ++r)
        avs[w][mt * 16 + g4 * 4 + r][dt * 16 + l15] = avacc[mt][dt][r];
  __syncthreads();
  for (int i = t; i < AG * HD; i += 256) {
    const int a = i >> 5, d = i & 31;
    const float L = Ls[0][a] + Ls[1][a] + Ls[2][a] + Ls[3][a];
    const float s = avs[0][a][d] + avs[1][a][d] + avs[2][a][d] + avs[3][a][d];
    const size_t si = (size_t)b * 768 + 512 + h * HD + d;
    av[((size_t)bh * AG + a) * HD + d] = (s / L) * sc[si] + sh[si];
  }
}

// ---------------- stage 2 (MFMA): Q affine folded; bf16 bias + output -------
__global__ __launch_bounds__(256) void stage2_kernel(
    const __bf16* __restrict__ Qt, const float* __restrict__ at,
    const float* __restrict__ av, const __bf16* __restrict__ ab2,
    const float* __restrict__ sc, const float* __restrict__ sh,
    __bf16* __restrict__ XO) {
  const int s = blockIdx.x;
  const int bh = blockIdx.y;
  const int b = bh >> 3, h = bh & 7;
  const int t = threadIdx.x;
  const int w = t >> 6, ln = t & 63;
  const int l15 = ln & 15, g4 = ln >> 4;

  __shared__ float atraw[64][33];
  __shared__ float scq_s[32], shq_s[32];
  __shared__ float cb2_s[64];
  __shared__ __bf16 atb[64][40];
  __shared__ __bf16 avbT[32][72];
  __shared__ __bf16 Es[4][16][72];
  __shared__ float Os[4][16][33];

  if (t < 32) {
    const size_t si = (size_t)b * 768 + h * HD + t;
    scq_s[t] = sc[si];
    shq_s[t] = sh[si];
  }
  for (int i = t; i < 64 * 32; i += 256) {
    const int d = i >> 6, a = i & 63;
    atraw[a][d] =
        (a < AG) ? at[((size_t)b * CC + h * HD + d) * AG + a] * SCALE : 0.f;
  }
  for (int i = t; i < 32 * 64; i += 256) {
    const int d = i >> 6, a = i & 63;
    const float v = (a < AG) ? av[((size_t)bh * AG + a) * HD + d] : 0.f;
    avbT[d][a] = (__bf16)v;
  }
  __syncthreads();
  if (t < 64) {
    float s2 = 0.f;
#pragma unroll
    for (int d = 0; d < HD; ++d) {
      const float v = atraw[t][d];
      s2 += v * shq_s[d];
      atb[t][d] = (__bf16)(v * scq_s[d]);
    }
    cb2_s[t] = s2;
  }
  __syncthreads();

  s16x8 at_fB[4];
  float q2b[4];
#pragma unroll
  for (int atile = 0; atile < 4; ++atile) {
    at_fB[atile] = *(const s16x8*)&atb[atile * 16 + l15][g4 * 8];
    q2b[atile] = cb2_s[atile * 16 + l15];
  }
  s16x8 av_fB[2][2];
#pragma unroll
  for (int dt = 0; dt < 2; ++dt)
#pragma unroll
    for (int ks = 0; ks < 2; ++ks)
      av_fB[dt][ks] = *(const s16x8*)&avbT[dt * 16 + l15][ks * 32 + g4 * 8];

  const __bf16* Qtb = Qt + (size_t)bh * NPIX * HD;
  const __bf16* abh = ab2 + (size_t)h * NPIX * 64;
  __bf16* Ob = XO + ((size_t)b * CC + h * HD) * NPIX;
  const f32x4 zz = {0.f, 0.f, 0.f, 0.f};
  const int nbase = s * 784;

  for (int ct = w; ct < 49; ct += 4) {
    const int n0 = nbase + ct * 16;
    const s16x8 qf = *(const s16x8*)&Qtb[(size_t)(n0 + l15) * HD + g4 * 8];
    f32x4 c[4];
#pragma unroll
    for (int atile = 0; atile < 4; ++atile)
      c[atile] = __builtin_amdgcn_mfma_f32_16x16x32_bf16(qf, at_fB[atile], zz, 0, 0, 0);
    float Lr[4];
#pragma unroll
    for (int r = 0; r < 4; ++r) {
      const int n = n0 + g4 * 4 + r;
      const __bf16* brow = &abh[(size_t)n * 64];
      float es[4];
#pragma unroll
      for (int atile = 0; atile < 4; ++atile) {
        const float e =
            __expf(c[atile][r] + (float)brow[atile * 16 + l15] + q2b[atile]);
        es[atile] = e;
        Es[w][g4 * 4 + r][atile * 16 + l15] = (__bf16)e;
      }
      float sr = (es[0] + es[1]) + (es[2] + es[3]);
      sr += __shfl_xor(sr, 1);
      sr += __shfl_xor(sr, 2);
      sr += __shfl_xor(sr, 4);
      sr += __shfl_xor(sr, 8);
      Lr[r] = sr;
    }
    asm volatile("s_waitcnt lgkmcnt(0)" ::: "memory");
    const s16x8 ef0 = *(const s16x8*)&Es[w][l15][g4 * 8];
    const s16x8 ef1 = *(const s16x8*)&Es[w][l15][32 + g4 * 8];
    f32x4 o0 = __builtin_amdgcn_mfma_f32_16x16x32_bf16(ef0, av_fB[0][0], zz, 0, 0, 0);
    o0 = __builtin_amdgcn_mfma_f32_16x16x32_bf16(ef1, av_fB[0][1], o0, 0, 0, 0);
    f32x4 o1 = __builtin_amdgcn_mfma_f32_16x16x32_bf16(ef0, av_fB[1][0], zz, 0, 0, 0);
    o1 = __builtin_amdgcn_mfma_f32_16x16x32_bf16(ef1, av_fB[1][1], o1, 0, 0, 0);
#pragma unroll
    for (int r = 0; r < 4; ++r) {
      const float inv = 1.f / Lr[r];
      Os[w][g4 * 4 + r][l15] = o0[r] * inv;
      Os[w][g4 * 4 + r][16 + l15] = o1[r] * inv;
    }
    asm volatile("s_waitcnt lgkmcnt(0)" ::: "memory");
#pragma unroll
    for (int it = 0; it < 8; ++it) {
      const int d = it * 4 + g4;
      Ob[(size_t)d * NPIX + n0 + l15] = (__bf16)Os[w][l15][d];
    }
  }
}

// ---------------- depthwise 3x3 conv, LDS-tiled, bf16 RMW into XO -----------
__global__ __launch_bounds__(256) void dwconv_kernel(
    const __bf16* __restrict__ V, const float* __restrict__ sc,
    const float* __restrict__ sh, const float* __restrict__ w,
    const float* __restrict__ bias, __bf16* __restrict__ XO) {
  const int bc = blockIdx.x;
  const int c = bc % CC;
  const int b = bc >> 8;
  const int tid = threadIdx.x;
  __shared__ float T[58][60];
  float* Tf = &T[0][0];
  for (int i = tid; i < 58 * 60; i += 256) Tf[i] = 0.f;
  __syncthreads();
  const size_t si = (size_t)b * 768 + 512 + c;
  const float scl = sc[si], shf = sh[si];
  const __bf16* src = V + (size_t)bc * NPIX;
  for (int i = tid; i < 392; i += 256) {
    const int y = i / 7, x8 = (i % 7) * 8;
    union { uint4 u; __bf16 e[8]; } raw;
    raw.u = *(const uint4*)&src[y * HDIM + x8];
#pragma unroll
    for (int j = 0; j < 8; ++j)
      T[y + 1][x8 + 1 + j] = (float)raw.e[j] * scl + shf;
  }
  __syncthreads();
  float k[9];
#pragma unroll
  for (int i = 0; i < 9; ++i) k[i] = w[c * 9 + i];
  const float bb = bias[c];
  __bf16* dst = XO + (size_t)bc * NPIX;
  for (int n = tid; n < NPIX; n += 256) {
    const int y = n / HDIM, x = n % HDIM;
    const float s = bb +
        k[0] * T[y][x]     + k[1] * T[y][x + 1]     + k[2] * T[y][x + 2] +
        k[3] * T[y + 1][x] + k[4] * T[y + 1][x + 1] + k[5] * T[y + 1][x + 2] +
        k[6] * T[y + 2][x] + k[7] * T[y + 2][x + 1] + k[8] * T[y + 2][x + 2];
    dst[n] = (__bf16)((float)dst[n] + s);
  }
}

// ---------------- host launch ------------------------------------------------
extern "C" void kernel_launch(void* const* d_in, const int* in_sizes, int n_in,
                              void* d_out, int out_size, void* d_ws,
                              size_t ws_size, hipStream_t stream) {
  const float* x     = (const float*)d_in[0];
  const float* q_w   = (const float*)d_in[1];
  const float* q_gw  = (const float*)d_in[2];
  const float* q_gb  = (const float*)d_in[3];
  const float* k_w   = (const float*)d_in[4];
  const float* k_gw  = (const float*)d_in[5];
  const float* k_gb  = (const float*)d_in[6];
  const float* v_w   = (const float*)d_in[7];
  const float* v_gw  = (const float*)d_in[8];
  const float* v_gb  = (const float*)d_in[9];
  const float* p_w   = (const float*)d_in[10];
  const float* p_gw  = (const float*)d_in[11];
  const float* p_gb  = (const float*)d_in[12];
  const float* dwc_w = (const float*)d_in[13];
  const float* dwc_b = (const float*)d_in[14];
  const float* an_b  = (const float*)d_in[15];
  const float* na_b  = (const float*)d_in[16];
  const float* ah_b  = (const float*)d_in[17];
  const float* aw_b  = (const float*)d_in[18];
  const float* ha_b  = (const float*)d_in[19];
  const float* wa_b  = (const float*)d_in[20];
  float* out = (float*)d_out;

  const size_t SZ_FEAT = (size_t)BB * CC * NPIX;       // 25,690,112 elements
  const size_t SZ_AT   = (size_t)BB * CC * AG;
  const size_t SZ_PBT  = (size_t)NHEADS * NPIX * 64;   // padded bias (x2, bf16)
  const size_t SZ_AV   = (size_t)BB * NHEADS * AG * HD;
  const size_t SZ_SC   = (size_t)BB * 768;             // GN scale/shift (x2)
  const size_t need =
      4 * SZ_FEAT * sizeof(__bf16) +
      (SZ_AT + SZ_AV + 2 * SZ_SC) * sizeof(float) +
      2 * SZ_PBT * sizeof(__bf16) + 1024 * 256 * sizeof(__bf16);
  if (ws_size < need) return;  // insufficient scratch: fail visibly

  __bf16* qbf = (__bf16*)d_ws;       // raw bf16 q from gemm (k,v contiguous)
  __bf16* kbf = qbf + SZ_FEAT;
  __bf16* vbf = kbf + SZ_FEAT;
  __bf16* xo  = vbf + SZ_FEAT;       // stage2 out + dwconv RMW (bf16)
  __bf16* pob = xo;                  // p-gemm bf16 out reuses xo (dead then)
  float* at  = (float*)(xo + SZ_FEAT);
  float* av  = at + SZ_AT;
  float* sc  = av + SZ_AV;
  float* sh  = sc + SZ_SC;
  __bf16* pbt = (__bf16*)(sh + SZ_SC);   // stage-1 bias, [h][n][64] bf16
  __bf16* ab2 = pbt + SZ_PBT;            // stage-2 bias, [h][n][64] bf16
  __bf16* wbf = ab2 + SZ_PBT;            // [1024][256]

  // d_out scratch timeline: xbf front (gemm input); Kt back half -> Qt
  // reuses after stage1; all dead before final gn writes d_out.
  __bf16* xbf = (__bf16*)d_out;
  __bf16* Kt  = (__bf16*)((char*)d_out + SZ_FEAT * 2);
  __bf16* Qt  = Kt;

  const dim3 ggrid(NGROUPS, BB);
  const dim3 tgrid(49, 4, BB);

  convert_w_kernel<<<dim3(256, 4), 256, 0, stream>>>(q_w, k_w, v_w, p_w, wbf);
  transpose_kernel<<<tgrid, 256, 0, stream>>>(x, xbf);
  gemm_kernel<__bf16><<<dim3(6, 49, BB), 256, 0, stream>>>(wbf, xbf, qbf, kbf,
                                                           vbf);
  qkvstat_kernel<<<dim3(96, BB), 256, 0, stream>>>(qbf, q_gw, q_gb, k_gw,
                                                   k_gb, v_gw, v_gb, sc, sh);

  pool_kernel<<<BB * CC, 64, 0, stream>>>(qbf, sc, sh, at);
  hipMemsetAsync(pbt, 0, SZ_PBT * sizeof(__bf16), stream);
  bias1_kernel<<<NHEADS * AG, 256, 0, stream>>>(an_b, ah_b, aw_b, pbt);
  fill_kernel<<<(int)(SZ_PBT / 8 + 255) / 256, 256, 0, stream>>>(
      ab2, (int)(SZ_PBT / 8));
  bias2_kernel<<<NHEADS * AG, 256, 0, stream>>>(na_b, ha_b, wa_b, ab2);

  tr_k_kernel<<<dim3(49, NHEADS, BB), 256, 0, stream>>>(kbf, Kt);
  stage1_kernel<<<BB * NHEADS, 256, 0, stream>>>(Kt, vbf, at, pbt, sc, sh, av);

  tr_k_kernel<<<dim3(49, NHEADS, BB), 256, 0, stream>>>(qbf, Qt);
  stage2_kernel<<<dim3(4, BB * NHEADS), 256, 0, stream>>>(Qt, at, av, ab2, sc,
                                                          sh, xo);
  dwconv_kernel<<<BB * CC, 256, 0, stream>>>(vbf, sc, sh, dwc_w, dwc_b, xo);

  transpose_b_kernel<<<tgrid, 256, 0, stream>>>(xo, xbf);
  gemm_kernel<__bf16><<<dim3(2, 49, BB), 256, 0, stream>>>(wbf + 768 * 256,
                                                           xbf, pob, pob, pob);
  gn_kernel<<<ggrid, 256, 0, stream>>>(pob, p_gw, p_gb, out);
}